// Round 20
// baseline (159.461 us; speedup 1.0000x reference)
//
#include <hip/hip_runtime.h>

typedef _Float16 f16;
typedef __attribute__((ext_vector_type(2))) _Float16 f16x2;
typedef __attribute__((ext_vector_type(4))) _Float16 f16x4;
typedef __attribute__((ext_vector_type(8))) _Float16 f16x8;
typedef __attribute__((ext_vector_type(4))) float f32x4;

#define MFMA16(A_, B_, C_) __builtin_amdgcn_mfma_f32_16x16x32_f16(A_, B_, C_, 0, 0, 0)
#define EXP2(x) __builtin_amdgcn_exp2f(x) /* bare v_exp_f32 (R12: OCML exp2f safe-path dominated VALU) */

#define NHEAD 16
#define SEQ 2048
#define DM 1024
#define DK 64
#define NBATCH 2
#define M_TOT (NBATCH * SEQ) /* 4096 */
#define CSC 0.18033688011112042f /* 0.125 * log2(e), folded into Wq/bq */

// direct-to-LDS 16B staging (per-lane global addr, linear LDS dest)
#define GLDS(gp, lp)                                                                     \
    __builtin_amdgcn_global_load_lds((const __attribute__((address_space(1))) void*)(gp), \
                                     (__attribute__((address_space(3))) void*)(lp), 16, 0, 0)

// ---------------- fused prep: mask bit-pack + X fp32->f16 + W transpose (1 launch) ----------------
__global__ __launch_bounds__(256) void prep_k(
    const int* __restrict__ mask, unsigned long long* __restrict__ mp,
    const float* __restrict__ xq, const float* __restrict__ xk, const float* __restrict__ xv,
    f16* __restrict__ oq, f16* __restrict__ ok, f16* __restrict__ ov,
    const float* __restrict__ Wq, const float* __restrict__ Wk,
    const float* __restrict__ Wv, const float* __restrict__ Wo, f16* __restrict__ Wt) {
    __shared__ float T[64][65];
    const int z = blockIdx.z, bx = blockIdx.x, tid = threadIdx.x;
    if (z < 3) {
        const float* src = z == 0 ? xq : (z == 1 ? xk : xv);
        f16* dst = z == 0 ? oq : (z == 1 ? ok : ov);
        size_t i = ((size_t)bx * 256 + tid) * 8;
        float4 a = *(const float4*)&src[i];
        float4 b = *(const float4*)&src[i + 4];
        f16x8 h;
        h[0] = (f16)a.x; h[1] = (f16)a.y; h[2] = (f16)a.z; h[3] = (f16)a.w;
        h[4] = (f16)b.x; h[5] = (f16)b.y; h[6] = (f16)b.z; h[7] = (f16)b.w;
        *(f16x8*)&dst[i] = h;
    } else if (z == 3) {
        if (bx >= 1024) return;
        const int zz = bx >> 8, t = bx & 255;
        const float* W = zz == 0 ? Wq : (zz == 1 ? Wk : (zz == 2 ? Wv : Wo));
        const float wsc = zz == 0 ? CSC : 1.0f;
        f16* out = Wt + (size_t)zz * DM * DM;
        const int k0 = (t >> 4) * 64, n0 = (t & 15) * 64;
        const int r = tid >> 2, q = tid & 3;
        const float4* s = (const float4*)&W[(size_t)(k0 + r) * DM + n0 + q * 16];
        float4 v0 = s[0], v1 = s[1], v2 = s[2], v3 = s[3];
        T[r][q * 16 + 0] = v0.x; T[r][q * 16 + 1] = v0.y; T[r][q * 16 + 2] = v0.z; T[r][q * 16 + 3] = v0.w;
        T[r][q * 16 + 4] = v1.x; T[r][q * 16 + 5] = v1.y; T[r][q * 16 + 6] = v1.z; T[r][q * 16 + 7] = v1.w;
        T[r][q * 16 + 8] = v2.x; T[r][q * 16 + 9] = v2.y; T[r][q * 16 + 10] = v2.z; T[r][q * 16 + 11] = v2.w;
        T[r][q * 16 + 12] = v3.x; T[r][q * 16 + 13] = v3.y; T[r][q * 16 + 14] = v3.z; T[r][q * 16 + 15] = v3.w;
        __syncthreads();
        f16x8 h0, h1;
#pragma unroll
        for (int j = 0; j < 8; ++j) {
            h0[j] = (f16)(T[q * 16 + j][r] * wsc);
            h1[j] = (f16)(T[q * 16 + 8 + j][r] * wsc);
        }
        *(f16x8*)&out[(size_t)(n0 + r) * DM + k0 + q * 16] = h0;
        *(f16x8*)&out[(size_t)(n0 + r) * DM + k0 + q * 16 + 8] = h1;
    } else {
        if (bx >= 512) return;
        int lane = tid & 63;
        int gw = (bx * 256 + tid) >> 6;
        const int nw = (512 * 256) >> 6;
        const int nwords = NBATCH * SEQ * (SEQ / 64);
        for (int w = gw; w < nwords; w += nw) {
            int v = mask[(size_t)w * 64 + lane];
            unsigned long long bits = __ballot(v != 0);
            if (lane == 0) mp[w] = bits;
        }
    }
}

// ---------------- f16 GEMM core: C[128x128] = A[128xK] . Bt[128xK]^T, K=1024 ----------------
__device__ __forceinline__ void gemm_core(const f16* __restrict__ A, const f16* __restrict__ Bt,
                                          int m0, int n0, f16* Al, f16* Bl, f32x4 acc[4][4], int tid) {
    const int lane = tid & 63;
    const int wv = tid >> 6;
    const int wr = wv >> 1, wc = wv & 1;
    const int g = lane >> 4, c = lane & 15;

    for (int k0 = 0; k0 < DM; k0 += 64) {
#pragma unroll
        for (int j = 0; j < 4; ++j) {
            int chunk = j * 256 + tid;  // 0..1023
            int row = chunk >> 3, cc = chunk & 7;
            int ccs = cc ^ (row & 7);
            GLDS(&A[(size_t)(m0 + row) * DM + k0 + ccs * 8], &Al[chunk * 8]);
        }
#pragma unroll
        for (int j = 0; j < 4; ++j) {
            int chunk = j * 256 + tid;
            int row = chunk >> 3, cc = chunk & 7;
            int ccs = cc ^ (row & 7);
            GLDS(&Bt[(size_t)(n0 + row) * DM + k0 + ccs * 8], &Bl[chunk * 8]);
        }
        __syncthreads();  // compiler drains vmcnt(0): tile staged
#pragma unroll
        for (int ks = 0; ks < 2; ++ks) {
            f16x8 af[4], bf[4];
#pragma unroll
            for (int mi = 0; mi < 4; ++mi) {
                int row = wr * 64 + mi * 16 + c;
                af[mi] = *(const f16x8*)&Al[row * 64 + ((ks * 4 + g) ^ (row & 7)) * 8];
            }
#pragma unroll
            for (int ni = 0; ni < 4; ++ni) {
                int row = wc * 64 + ni * 16 + c;
                bf[ni] = *(const f16x8*)&Bl[row * 64 + ((ks * 4 + g) ^ (row & 7)) * 8];
            }
#pragma unroll
            for (int mi = 0; mi < 4; ++mi)
#pragma unroll
                for (int ni = 0; ni < 4; ++ni)
                    acc[mi][ni] = MFMA16(af[mi], bf[ni], acc[mi][ni]);
        }
        __syncthreads();  // frag reads done before next stage overwrites
    }
}

// XCD-aware chunked block swizzle (T1): 256 wg per z-slice, 8 XCDs, 32 wg/XCD chunk.
__device__ __forceinline__ void xcd_swizzle(int& bx, int& by, int gdx) {
    int lin = by * gdx + bx;
    int nl = (lin & 7) * 32 + (lin >> 3); // bijective: 256 = 8*32
    bx = nl % gdx;
    by = nl / gdx;
}

// ---------------- QKV projection: f16 Xh . Wt + b -> Q/K per-head [B,H,S,DK]; V -> VhT [B,H,DK,S] ----------------
__global__ __launch_bounds__(256) void gemm_qkv2_k(
    const f16* __restrict__ Xq, const f16* __restrict__ Xk, const f16* __restrict__ Xv,
    const f16* __restrict__ Wt, const float* __restrict__ bq, const float* __restrict__ bk,
    const float* __restrict__ bv, f16* __restrict__ Qh, f16* __restrict__ Kh, f16* __restrict__ VhT) {
    __shared__ f16 Al[128 * 64];
    __shared__ f16 Bl[128 * 64];
    const int which = blockIdx.z;
    const f16* A = which == 0 ? Xq : (which == 1 ? Xk : Xv);
    const f16* Bt = Wt + (size_t)which * DM * DM;
    const float* bias = which == 0 ? bq : (which == 1 ? bk : bv);

    const int tid = threadIdx.x, lane = tid & 63, wv = tid >> 6;
    const int wr = wv >> 1, wc = wv & 1, g = lane >> 4, c = lane & 15;
    int bx = blockIdx.x, by = blockIdx.y;
    xcd_swizzle(bx, by, gridDim.x);
    const int m0 = by * 128, n0 = bx * 128;

    f32x4 acc[4][4] = {};
    gemm_core(A, Bt, m0, n0, Al, Bl, acc, tid);

    const float bsc = which == 0 ? CSC : 1.0f; // CSC folded into Wq; fold into bq too
    if (which == 2) {
        // V epilogue writes transposed VhT[b,h,d,s]: 4 consecutive m = consecutive s -> f16x4
#pragma unroll
        for (int ni = 0; ni < 4; ++ni) {
            int n = n0 + wc * 64 + ni * 16 + c;
            float bias_n = bias[n];
            int hh = n >> 6, d = n & 63;
#pragma unroll
            for (int mi = 0; mi < 4; ++mi) {
                int mbase = m0 + wr * 64 + mi * 16 + g * 4;
                int bb = mbase >> 11, s = mbase & (SEQ - 1);
                f16x4 o;
#pragma unroll
                for (int r = 0; r < 4; ++r) o[r] = (f16)(acc[mi][ni][r] + bias_n);
                *(f16x4*)&VhT[(((size_t)(bb * NHEAD + hh)) * DK + d) * SEQ + s] = o;
            }
        }
    } else {
        f16* OUT = which == 0 ? Qh : Kh;
#pragma unroll
        for (int ni = 0; ni < 4; ++ni) {
            int n = n0 + wc * 64 + ni * 16 + c;
            float bias_n = bias[n] * bsc;
            int hh = n >> 6, d = n & 63;
#pragma unroll
            for (int mi = 0; mi < 4; ++mi) {
                int mbase = m0 + wr * 64 + mi * 16 + g * 4;
#pragma unroll
                for (int r = 0; r < 4; ++r) {
                    int m = mbase + r;
                    int bb = m >> 11, s = m & (SEQ - 1);
                    OUT[(((size_t)(bb * NHEAD + hh)) * SEQ + s) * DK + d] = (f16)(acc[mi][ni][r] + bias_n);
                }
            }
        }
    }
}

// ---------------- output projection: f16 Xo . Wto + bo -> fp32 [M][DM] ----------------
__global__ __launch_bounds__(256) void gemm_out2_k(
    const f16* __restrict__ Xo, const f16* __restrict__ Wto, const float* __restrict__ bo,
    float* __restrict__ OUT) {
    __shared__ f16 Al[128 * 64];
    __shared__ f16 Bl[128 * 64];
    const int tid = threadIdx.x, lane = tid & 63, wv = tid >> 6;
    const int wr = wv >> 1, wc = wv & 1, g = lane >> 4, c = lane & 15;
    int bx = blockIdx.x, by = blockIdx.y;
    xcd_swizzle(bx, by, gridDim.x);
    const int m0 = by * 128, n0 = bx * 128;

    f32x4 acc[4][4] = {};
    gemm_core(Xo, Wto, m0, n0, Al, Bl, acc, tid);

#pragma unroll
    for (int ni = 0; ni < 4; ++ni) {
        int n = n0 + wc * 64 + ni * 16 + c;
        float bias_n = bo[n];
#pragma unroll
        for (int mi = 0; mi < 4; ++mi) {
            int mbase = m0 + wr * 64 + mi * 16 + g * 4;
#pragma unroll
            for (int r = 0; r < 4; ++r) {
                int m = mbase + r;
                OUT[(size_t)m * DM + n] = acc[mi][ni][r] + bias_n;
            }
        }
    }
}

// ---------------- flash attention: permuted-K, split-K x2, 2 q-groups per wave ----------------
// QBLK=256: each wave owns 32 q-rows (2 groups of 16). K/V fragments are read from LDS
// ONCE per kt and shared across both q-groups -> LDS read traffic and barrier count
// HALVED vs QBLK=128 (R19: 2.1GB LDS reads ~ 30us floor was half the kernel).
// Register discipline: QK^T both groups (incremental K reads, K dies) -> softmax+pack
// (sc dies) -> PV both groups (incremental V reads). ~115 VGPR peak; launch_bounds
// (512,4) caps at 128 >= need (R4 lesson: never cap below need).
// PERMUTED K (R19): LDS key-slot s holds key kap(s); QK^T D-layout IS PV B-frag layout;
// mask bit = (nk&1)*32 + g*8 + (nk>>1)*4 + r. FIXED m=0 softmax (R9), bare v_exp_f32
// (R12), l-reduce deferred, Q pre-scaled by CSC. Decode keeps lin&7==hh&7 (XCD affinity).
#define QBLK 256
#define NHALF 2
#define KTH (SEQ / 64 / NHALF) /* 16 */

__global__ __launch_bounds__(512, 4) void attn_k(
    const f16* __restrict__ Qh, const f16* __restrict__ Kh, const f16* __restrict__ VhT,
    const unsigned long long* __restrict__ mp, f16* __restrict__ O0, f16* __restrict__ O1,
    float2* __restrict__ ml) {
    __shared__ f16 Kl[2][4096]; // [key-slot][d] tiles, swizzled 16B chunks (16 KB)
    __shared__ f16 Vl[2][4096]; // [d][key] tiles (from VhT), swizzled (16 KB)

    const int tid = threadIdx.x, lane = tid & 63, wv = tid >> 6;
    const int g = lane >> 4, c = lane & 15;
    const int lin = blockIdx.x;               // 512 blocks
    const int key = lin & 31;                 // b*16 + hh : lin&7 == hh&7 -> XCD affinity
    const int half = (lin >> 5) & 1;
    const int qt = lin >> 6;                  // 0..7
    const int hh = key & (NHEAD - 1), b = key >> 4;
    const size_t headoff = ((size_t)(b * NHEAD + hh)) * SEQ * DK;
    const f16* Qb = Qh + headoff;
    const f16* Kb = Kh + headoff + (size_t)half * (SEQ / NHALF) * DK;
    const f16* VbT = VhT + headoff + (size_t)half * (SEQ / NHALF); // [DK][SEQ] rows

    // staging: 512 chunks of 16B per tile, 1 per thread per tile
    const int srow = tid >> 3, scc = (tid & 7) ^ (srow & 7);
    // permuted source key for K-slot srow
    const int kap = ((srow >> 4) & 1) * 32 + ((srow >> 2) & 3) * 8 + ((srow >> 5) & 1) * 4 + (srow & 3);

#define STAGE_ATTN(jj, pp)                                                      \
    do {                                                                        \
        GLDS(&Kb[(size_t)((jj)*64 + kap) * DK + scc * 8], &Kl[pp][tid * 8]);    \
        GLDS(&VbT[(size_t)srow * SEQ + (jj)*64 + scc * 8], &Vl[pp][tid * 8]);   \
    } while (0)

    const int qrowA = qt * QBLK + wv * 32 + c;       // q-group 0
    const int qrowB = qrowA + 16;                    // q-group 1
    f16x8 bqA0 = *(const f16x8*)&Qb[(size_t)qrowA * DK + g * 8];      // pre-scaled by CSC
    f16x8 bqA1 = *(const f16x8*)&Qb[(size_t)qrowA * DK + 32 + g * 8];
    f16x8 bqB0 = *(const f16x8*)&Qb[(size_t)qrowB * DK + g * 8];
    f16x8 bqB1 = *(const f16x8*)&Qb[(size_t)qrowB * DK + 32 + g * 8];

    f32x4 accA[4] = {}, accB[4] = {};
    float lA = 0.f, lB = 0.f;

    const unsigned long long* mrowA = mp + ((size_t)b * SEQ + qrowA) * (SEQ / 64) + half * KTH;
    const unsigned long long* mrowB = mp + ((size_t)b * SEQ + qrowB) * (SEQ / 64) + half * KTH;
    unsigned long long wqA = mrowA[0], wqB = mrowB[0];

    STAGE_ATTN(0, 0);
    int p = 0;
    for (int j = 0; j < KTH; ++j) {
        __syncthreads(); // drains vmcnt(0): tile j staged in buf p; buf p^1 reads (iter j-1) done
        if (j + 1 < KTH) STAGE_ATTN(j + 1, p ^ 1); // in flight across the whole compute phase
        unsigned long long wqA_n = (j + 1 < KTH) ? mrowA[j + 1] : 0ull;
        unsigned long long wqB_n = (j + 1 < KTH) ? mrowB[j + 1] : 0ull;

        // QK^T both q-groups: K frags read ONCE, shared (halves LDS reads vs 1 qg/wave)
        f32x4 sA[4], sB[4];
        __builtin_amdgcn_s_setprio(1);
#pragma unroll
        for (int nk = 0; nk < 4; ++nk) {
            int row = nk * 16 + c;
            f16x8 k0 = *(const f16x8*)&Kl[p][row * 64 + ((g ^ (row & 7)) * 8)];
            f16x8 k1 = *(const f16x8*)&Kl[p][row * 64 + (((4 + g) ^ (row & 7)) * 8)];
            f32x4 z = {};
            z = MFMA16(k0, bqA0, z);
            z = MFMA16(k1, bqA1, z);
            sA[nk] = z;
            f32x4 y = {};
            y = MFMA16(k0, bqB0, y);
            y = MFMA16(k1, bqB1, y);
            sB[nk] = y;
        }
        __builtin_amdgcn_s_setprio(0);

        // fixed-m softmax on permuted slots; mask bit = (nk&1)*32 + (nk>>1)*4 + r after >>(g*8)
        unsigned long long wgA = wqA >> (g * 8), wgB = wqB >> (g * 8);
        float psA = 0.f, psB = 0.f;
#pragma unroll
        for (int nk = 0; nk < 4; ++nk) {
            unsigned int nibA = (unsigned int)(wgA >> ((nk & 1) * 32 + (nk >> 1) * 4)) & 0xFu;
            unsigned int nibB = (unsigned int)(wgB >> ((nk & 1) * 32 + (nk >> 1) * 4)) & 0xFu;
#pragma unroll
            for (int r = 0; r < 4; ++r) {
                float pa = EXP2(sA[nk][r]);
                pa = (nibA & (1u << r)) ? pa : 0.f;
                sA[nk][r] = pa;
                psA += pa;
                float pb = EXP2(sB[nk][r]);
                pb = (nibB & (1u << r)) ? pb : 0.f;
                sB[nk][r] = pb;
                psB += pb;
            }
        }
        lA += psA;
        lB += psB;

        // in-lane pack: D-layout (permuted) IS the PV B-frag layout
        f16x8 pA0, pA1, pB0, pB1;
#pragma unroll
        for (int j2 = 0; j2 < 2; ++j2)
#pragma unroll
            for (int r = 0; r < 4; ++r) {
                pA0[j2 * 4 + r] = (f16)sA[j2 * 2][r];
                pA1[j2 * 4 + r] = (f16)sA[j2 * 2 + 1][r];
                pB0[j2 * 4 + r] = (f16)sB[j2 * 2][r];
                pB1[j2 * 4 + r] = (f16)sB[j2 * 2 + 1][r];
            }

        // PV both q-groups: V frags read ONCE, shared
        __builtin_amdgcn_s_setprio(1);
#pragma unroll
        for (int nd = 0; nd < 4; ++nd) {
            int row = nd * 16 + c;
            f16x8 v0 = *(const f16x8*)&Vl[p][row * 64 + ((g ^ (row & 7)) * 8)];
            f16x8 v1 = *(const f16x8*)&Vl[p][row * 64 + (((4 + g) ^ (row & 7)) * 8)];
            accA[nd] = MFMA16(v0, pA0, accA[nd]);
            accA[nd] = MFMA16(v1, pA1, accA[nd]);
            accB[nd] = MFMA16(v0, pB0, accB[nd]);
            accB[nd] = MFMA16(v1, pB1, accB[nd]);
        }
        __builtin_amdgcn_s_setprio(0);

        wqA = wqA_n;
        wqB = wqB_n;
        p ^= 1;
    }

    // deferred l reduction across the 4 g-lanes holding each q-row
    lA += __shfl_xor(lA, 16);
    lA += __shfl_xor(lA, 32);
    lB += __shfl_xor(lB, 16);
    lB += __shfl_xor(lB, 32);

    f16* Opart = half ? O1 : O0;
    {
        float invA = lA > 0.f ? 1.0f / lA : 0.f;
        float invB = lB > 0.f ? 1.0f / lB : 0.f;
        size_t hrowA = headoff / DK + qrowA;
        size_t hrowB = headoff / DK + qrowB;
#pragma unroll
        for (int nd = 0; nd < 4; ++nd) {
            f16x4 oA, oB;
#pragma unroll
            for (int r = 0; r < 4; ++r) {
                oA[r] = (f16)(accA[nd][r] * invA);
                oB[r] = (f16)(accB[nd][r] * invB);
            }
            *(f16x4*)&Opart[hrowA * DK + nd * 16 + g * 4] = oA;
            *(f16x4*)&Opart[hrowB * DK + nd * 16 + g * 4] = oB;
        }
        if (g == 0) {
            ml[(size_t)half * (M_TOT * NHEAD) + hrowA] = make_float2(0.f, lA);
            ml[(size_t)half * (M_TOT * NHEAD) + hrowB] = make_float2(0.f, lB);
        }
    }
#undef STAGE_ATTN
}

// ---------------- combine split-K partials -> Xo f16 [B,S,DM] ----------------
__global__ __launch_bounds__(256) void combine_k(const f16* __restrict__ O0, const f16* __restrict__ O1,
                                                 const float2* __restrict__ ml, f16* __restrict__ Xo) {
    const int row = blockIdx.x * 32 + (threadIdx.x >> 3);
    const int d0 = (threadIdx.x & 7) * 8;
    const int b = row >> 15, hh = (row >> 11) & 15, q = row & (SEQ - 1);
    float2 a = ml[row];
    float2 bb = ml[(M_TOT * NHEAD) + row];
    float m = fmaxf(a.x, bb.x);
    float w0 = a.y * EXP2(a.x - m);
    float w1 = bb.y * EXP2(bb.x - m);
    float inv = 1.0f / (w0 + w1);
    float a0 = w0 * inv, a1 = w1 * inv;
    f16x8 o0 = *(const f16x8*)&O0[(size_t)row * DK + d0];
    f16x8 o1 = *(const f16x8*)&O1[(size_t)row * DK + d0];
    f16x8 o;
#pragma unroll
    for (int i = 0; i < 8; ++i) o[i] = (f16)(a0 * (float)o0[i] + a1 * (float)o1[i]);
    *(f16x8*)&Xo[((size_t)(b * SEQ + q)) * DM + hh * DK + d0] = o;
}

extern "C" void kernel_launch(void* const* d_in, const int* in_sizes, int n_in,
                              void* d_out, int out_size, void* d_ws, size_t ws_size,
                              hipStream_t stream) {
    const float* query = (const float*)d_in[0];
    const float* key_ = (const float*)d_in[1];
    const float* value = (const float*)d_in[2];
    const int* mask = (const int*)d_in[3];
    const float* Wq = (const float*)d_in[4];
    const float* bq = (const float*)d_in[5];
    const float* Wk = (const float*)d_in[6];
    const float* bk = (const float*)d_in[7];
    const float* Wv = (const float*)d_in[8];
    const float* bv = (const float*)d_in[9];
    const float* Wo = (const float*)d_in[10];
    const float* bo = (const float*)d_in[11];
    float* out = (float*)d_out;

    // ws layout (58 MiB): mp(1M) | Qh | Kh | VhT | Xhq(->Xo) | Xhk/O0 | Xhv/O1 | Wt | ml(1M)
    char* ws = (char*)d_ws;
    const size_t headsz = (size_t)NBATCH * NHEAD * SEQ * DK * sizeof(f16); // 8 MiB
    unsigned long long* mp = (unsigned long long*)(ws);
    f16* Qh = (f16*)(ws + (1 << 20));
    f16* Kh = (f16*)(ws + (1 << 20) + headsz);
    f16* VhT = (f16*)(ws + (1 << 20) + 2 * headsz);
    f16* Xhq = (f16*)(ws + (1 << 20) + 3 * headsz);
    f16* Xhk = (f16*)(ws + (1 << 20) + 4 * headsz);
    f16* Xhv = (f16*)(ws + (1 << 20) + 5 * headsz);
    f16* Wt = (f16*)(ws + (1 << 20) + 6 * headsz); // 4 x [1024][1024] f16
    float2* ml = (float2*)(ws + (1 << 20) + 7 * headsz);
    f16* Xo = Xhq;

    hipLaunchKernelGGL(prep_k, dim3(M_TOT * DM / (8 * 256), 1, 5), dim3(256), 0, stream,
                       mask, mp, query, key_, value, Xhq, Xhk, Xhv, Wq, Wk, Wv, Wo, Wt);
    hipLaunchKernelGGL(gemm_qkv2_k, dim3(DM / 128, M_TOT / 128, 3), dim3(256), 0, stream,
                       Xhq, Xhk, Xhv, Wt, bq, bk, bv, Qh, Kh, VhT);
    hipLaunchKernelGGL(attn_k, dim3(SEQ / QBLK * NHEAD * NBATCH * NHALF), dim3(512), 0, stream,
                       Qh, Kh, VhT, mp, Xhk, Xhv, ml);
    hipLaunchKernelGGL(combine_k, dim3(M_TOT * NHEAD / 32), dim3(256), 0, stream, Xhk, Xhv, ml, Xo);
    hipLaunchKernelGGL(gemm_out2_k, dim3(DM / 128, M_TOT / 128), dim3(256), 0, stream,
                       Xo, Wt + (size_t)3 * DM * DM, bo, out);
}

// Round 21
// 155.598 us; speedup vs baseline: 1.0248x; 1.0248x over previous
//
#include <hip/hip_runtime.h>

typedef _Float16 f16;
typedef __attribute__((ext_vector_type(2))) _Float16 f16x2;
typedef __attribute__((ext_vector_type(4))) _Float16 f16x4;
typedef __attribute__((ext_vector_type(8))) _Float16 f16x8;
typedef __attribute__((ext_vector_type(4))) float f32x4;

#define MFMA16(A_, B_, C_) __builtin_amdgcn_mfma_f32_16x16x32_f16(A_, B_, C_, 0, 0, 0)
#define EXP2(x) __builtin_amdgcn_exp2f(x) /* bare v_exp_f32 (R12: OCML exp2f safe-path dominated VALU) */

#define NHEAD 16
#define SEQ 2048
#define DM 1024
#define DK 64
#define NBATCH 2
#define M_TOT (NBATCH * SEQ) /* 4096 */
#define CSC 0.18033688011112042f /* 0.125 * log2(e), folded into Wq/bq */

// direct-to-LDS 16B staging (per-lane global addr, linear LDS dest)
#define GLDS(gp, lp)                                                                     \
    __builtin_amdgcn_global_load_lds((const __attribute__((address_space(1))) void*)(gp), \
                                     (__attribute__((address_space(3))) void*)(lp), 16, 0, 0)

// ---------------- fused prep: mask bit-pack + X fp32->f16 + W transpose (1 launch) ----------------
__global__ __launch_bounds__(256) void prep_k(
    const int* __restrict__ mask, unsigned long long* __restrict__ mp,
    const float* __restrict__ xq, const float* __restrict__ xk, const float* __restrict__ xv,
    f16* __restrict__ oq, f16* __restrict__ ok, f16* __restrict__ ov,
    const float* __restrict__ Wq, const float* __restrict__ Wk,
    const float* __restrict__ Wv, const float* __restrict__ Wo, f16* __restrict__ Wt) {
    __shared__ float T[64][65];
    const int z = blockIdx.z, bx = blockIdx.x, tid = threadIdx.x;
    if (z < 3) {
        const float* src = z == 0 ? xq : (z == 1 ? xk : xv);
        f16* dst = z == 0 ? oq : (z == 1 ? ok : ov);
        size_t i = ((size_t)bx * 256 + tid) * 8;
        float4 a = *(const float4*)&src[i];
        float4 b = *(const float4*)&src[i + 4];
        f16x8 h;
        h[0] = (f16)a.x; h[1] = (f16)a.y; h[2] = (f16)a.z; h[3] = (f16)a.w;
        h[4] = (f16)b.x; h[5] = (f16)b.y; h[6] = (f16)b.z; h[7] = (f16)b.w;
        *(f16x8*)&dst[i] = h;
    } else if (z == 3) {
        if (bx >= 1024) return;
        const int zz = bx >> 8, t = bx & 255;
        const float* W = zz == 0 ? Wq : (zz == 1 ? Wk : (zz == 2 ? Wv : Wo));
        const float wsc = zz == 0 ? CSC : 1.0f;
        f16* out = Wt + (size_t)zz * DM * DM;
        const int k0 = (t >> 4) * 64, n0 = (t & 15) * 64;
        const int r = tid >> 2, q = tid & 3;
        const float4* s = (const float4*)&W[(size_t)(k0 + r) * DM + n0 + q * 16];
        float4 v0 = s[0], v1 = s[1], v2 = s[2], v3 = s[3];
        T[r][q * 16 + 0] = v0.x; T[r][q * 16 + 1] = v0.y; T[r][q * 16 + 2] = v0.z; T[r][q * 16 + 3] = v0.w;
        T[r][q * 16 + 4] = v1.x; T[r][q * 16 + 5] = v1.y; T[r][q * 16 + 6] = v1.z; T[r][q * 16 + 7] = v1.w;
        T[r][q * 16 + 8] = v2.x; T[r][q * 16 + 9] = v2.y; T[r][q * 16 + 10] = v2.z; T[r][q * 16 + 11] = v2.w;
        T[r][q * 16 + 12] = v3.x; T[r][q * 16 + 13] = v3.y; T[r][q * 16 + 14] = v3.z; T[r][q * 16 + 15] = v3.w;
        __syncthreads();
        f16x8 h0, h1;
#pragma unroll
        for (int j = 0; j < 8; ++j) {
            h0[j] = (f16)(T[q * 16 + j][r] * wsc);
            h1[j] = (f16)(T[q * 16 + 8 + j][r] * wsc);
        }
        *(f16x8*)&out[(size_t)(n0 + r) * DM + k0 + q * 16] = h0;
        *(f16x8*)&out[(size_t)(n0 + r) * DM + k0 + q * 16 + 8] = h1;
    } else {
        if (bx >= 512) return;
        int lane = tid & 63;
        int gw = (bx * 256 + tid) >> 6;
        const int nw = (512 * 256) >> 6;
        const int nwords = NBATCH * SEQ * (SEQ / 64);
        for (int w = gw; w < nwords; w += nw) {
            int v = mask[(size_t)w * 64 + lane];
            unsigned long long bits = __ballot(v != 0);
            if (lane == 0) mp[w] = bits;
        }
    }
}

// ---------------- f16 GEMM core: C[128x128] = A[128xK] . Bt[128xK]^T, K=1024 ----------------
__device__ __forceinline__ void gemm_core(const f16* __restrict__ A, const f16* __restrict__ Bt,
                                          int m0, int n0, f16* Al, f16* Bl, f32x4 acc[4][4], int tid) {
    const int lane = tid & 63;
    const int wv = tid >> 6;
    const int wr = wv >> 1, wc = wv & 1;
    const int g = lane >> 4, c = lane & 15;

    for (int k0 = 0; k0 < DM; k0 += 64) {
#pragma unroll
        for (int j = 0; j < 4; ++j) {
            int chunk = j * 256 + tid;  // 0..1023
            int row = chunk >> 3, cc = chunk & 7;
            int ccs = cc ^ (row & 7);
            GLDS(&A[(size_t)(m0 + row) * DM + k0 + ccs * 8], &Al[chunk * 8]);
        }
#pragma unroll
        for (int j = 0; j < 4; ++j) {
            int chunk = j * 256 + tid;
            int row = chunk >> 3, cc = chunk & 7;
            int ccs = cc ^ (row & 7);
            GLDS(&Bt[(size_t)(n0 + row) * DM + k0 + ccs * 8], &Bl[chunk * 8]);
        }
        __syncthreads();  // compiler drains vmcnt(0): tile staged
#pragma unroll
        for (int ks = 0; ks < 2; ++ks) {
            f16x8 af[4], bf[4];
#pragma unroll
            for (int mi = 0; mi < 4; ++mi) {
                int row = wr * 64 + mi * 16 + c;
                af[mi] = *(const f16x8*)&Al[row * 64 + ((ks * 4 + g) ^ (row & 7)) * 8];
            }
#pragma unroll
            for (int ni = 0; ni < 4; ++ni) {
                int row = wc * 64 + ni * 16 + c;
                bf[ni] = *(const f16x8*)&Bl[row * 64 + ((ks * 4 + g) ^ (row & 7)) * 8];
            }
#pragma unroll
            for (int mi = 0; mi < 4; ++mi)
#pragma unroll
                for (int ni = 0; ni < 4; ++ni)
                    acc[mi][ni] = MFMA16(af[mi], bf[ni], acc[mi][ni]);
        }
        __syncthreads();  // frag reads done before next stage overwrites
    }
}

// XCD-aware chunked block swizzle (T1): 256 wg per z-slice, 8 XCDs, 32 wg/XCD chunk.
__device__ __forceinline__ void xcd_swizzle(int& bx, int& by, int gdx) {
    int lin = by * gdx + bx;
    int nl = (lin & 7) * 32 + (lin >> 3); // bijective: 256 = 8*32
    bx = nl % gdx;
    by = nl / gdx;
}

// ---------------- QKV projection: f16 Xh . Wt + b -> Q/K per-head [B,H,S,DK]; V -> VhT [B,H,DK,S] ----------------
__global__ __launch_bounds__(256) void gemm_qkv2_k(
    const f16* __restrict__ Xq, const f16* __restrict__ Xk, const f16* __restrict__ Xv,
    const f16* __restrict__ Wt, const float* __restrict__ bq, const float* __restrict__ bk,
    const float* __restrict__ bv, f16* __restrict__ Qh, f16* __restrict__ Kh, f16* __restrict__ VhT) {
    __shared__ f16 Al[128 * 64];
    __shared__ f16 Bl[128 * 64];
    const int which = blockIdx.z;
    const f16* A = which == 0 ? Xq : (which == 1 ? Xk : Xv);
    const f16* Bt = Wt + (size_t)which * DM * DM;
    const float* bias = which == 0 ? bq : (which == 1 ? bk : bv);

    const int tid = threadIdx.x, lane = tid & 63, wv = tid >> 6;
    const int wr = wv >> 1, wc = wv & 1, g = lane >> 4, c = lane & 15;
    int bx = blockIdx.x, by = blockIdx.y;
    xcd_swizzle(bx, by, gridDim.x);
    const int m0 = by * 128, n0 = bx * 128;

    f32x4 acc[4][4] = {};
    gemm_core(A, Bt, m0, n0, Al, Bl, acc, tid);

    const float bsc = which == 0 ? CSC : 1.0f; // CSC folded into Wq; fold into bq too
    if (which == 2) {
        // V epilogue writes transposed VhT[b,h,d,s]: 4 consecutive m = consecutive s -> f16x4
#pragma unroll
        for (int ni = 0; ni < 4; ++ni) {
            int n = n0 + wc * 64 + ni * 16 + c;
            float bias_n = bias[n];
            int hh = n >> 6, d = n & 63;
#pragma unroll
            for (int mi = 0; mi < 4; ++mi) {
                int mbase = m0 + wr * 64 + mi * 16 + g * 4;
                int bb = mbase >> 11, s = mbase & (SEQ - 1);
                f16x4 o;
#pragma unroll
                for (int r = 0; r < 4; ++r) o[r] = (f16)(acc[mi][ni][r] + bias_n);
                *(f16x4*)&VhT[(((size_t)(bb * NHEAD + hh)) * DK + d) * SEQ + s] = o;
            }
        }
    } else {
        f16* OUT = which == 0 ? Qh : Kh;
#pragma unroll
        for (int ni = 0; ni < 4; ++ni) {
            int n = n0 + wc * 64 + ni * 16 + c;
            float bias_n = bias[n] * bsc;
            int hh = n >> 6, d = n & 63;
#pragma unroll
            for (int mi = 0; mi < 4; ++mi) {
                int mbase = m0 + wr * 64 + mi * 16 + g * 4;
#pragma unroll
                for (int r = 0; r < 4; ++r) {
                    int m = mbase + r;
                    int bb = m >> 11, s = m & (SEQ - 1);
                    OUT[(((size_t)(bb * NHEAD + hh)) * SEQ + s) * DK + d] = (f16)(acc[mi][ni][r] + bias_n);
                }
            }
        }
    }
}

// ---------------- output projection: f16 Xo . Wto + bo -> fp32 [M][DM] ----------------
__global__ __launch_bounds__(256) void gemm_out2_k(
    const f16* __restrict__ Xo, const f16* __restrict__ Wto, const float* __restrict__ bo,
    float* __restrict__ OUT) {
    __shared__ f16 Al[128 * 64];
    __shared__ f16 Bl[128 * 64];
    const int tid = threadIdx.x, lane = tid & 63, wv = tid >> 6;
    const int wr = wv >> 1, wc = wv & 1, g = lane >> 4, c = lane & 15;
    int bx = blockIdx.x, by = blockIdx.y;
    xcd_swizzle(bx, by, gridDim.x);
    const int m0 = by * 128, n0 = bx * 128;

    f32x4 acc[4][4] = {};
    gemm_core(Xo, Wto, m0, n0, Al, Bl, acc, tid);

#pragma unroll
    for (int ni = 0; ni < 4; ++ni) {
        int n = n0 + wc * 64 + ni * 16 + c;
        float bias_n = bo[n];
#pragma unroll
        for (int mi = 0; mi < 4; ++mi) {
            int mbase = m0 + wr * 64 + mi * 16 + g * 4;
#pragma unroll
            for (int r = 0; r < 4; ++r) {
                int m = mbase + r;
                OUT[(size_t)m * DM + n] = acc[mi][ni][r] + bias_n;
            }
        }
    }
}

// ---------------- flash attention: SINGLE PASS + permuted-K (best measured combo) ----------------
// R20 post-mortem: split-K's combine (+4us) ate the permuted-K win; R18's single-pass
// total (157.5) beat R19/R20 (159.1/159.5). This kernel = R18 structure + R19 permuted-K.
// PERMUTED K: LDS key-slot s (bits s5..s0) holds key kap(s) = s4*32 + (s3s2)*8 + s5*4 + (s1s0).
// QK^T's D-layout output IS PV's B-frag layout: pb_ks[j] = sc[2*(j>>2)+ks][j&3] — in-lane
// f32->f16 pack, no LDS/shfl roundtrip (R19: attn -5us, conflicts 0, LDS 33KB).
// Single pass over 32 kt, normalized Xo written directly (no combine, no partial-O traffic).
// Decode keeps lin&31 = b*16+hh -> XCD affinity (R18: FETCH at ideal 16MB).
// FIXED m=0 softmax (R9), bare v_exp_f32 (R12), l-reduce deferred, Q pre-scaled by CSC.
#define QBLK 128
#define KT_ALL (SEQ / 64) /* 32 */

__global__ __launch_bounds__(512) void attn_k(
    const f16* __restrict__ Qh, const f16* __restrict__ Kh, const f16* __restrict__ VhT,
    const unsigned long long* __restrict__ mp, f16* __restrict__ Xo) {
    __shared__ f16 Kl[2][4096]; // [key-slot][d] tiles, swizzled 16B chunks (16 KB)
    __shared__ f16 Vl[2][4096]; // [d][key] tiles (from VhT), swizzled (16 KB)

    const int tid = threadIdx.x, lane = tid & 63, wv = tid >> 6;
    const int g = lane >> 4, c = lane & 15;
    const int lin = blockIdx.x;          // 512 blocks
    const int key = lin & 31;            // b*16 + hh : lin&7 == hh&7 -> XCD affinity
    const int qt = lin >> 5;             // 0..15
    const int hh = key & (NHEAD - 1), b = key >> 4;
    const size_t headoff = ((size_t)(b * NHEAD + hh)) * SEQ * DK;
    const f16* Qb = Qh + headoff;
    const f16* Kb = Kh + headoff;
    const f16* VbT = VhT + headoff; // [DK][SEQ] rows

    // staging: 512 chunks of 16B per tile, 1 per thread per tile
    const int srow = tid >> 3, scc = (tid & 7) ^ (srow & 7);
    // permuted source key for K-slot srow
    const int kap = ((srow >> 4) & 1) * 32 + ((srow >> 2) & 3) * 8 + ((srow >> 5) & 1) * 4 + (srow & 3);

#define STAGE_ATTN(jj, pp)                                                      \
    do {                                                                        \
        GLDS(&Kb[(size_t)((jj)*64 + kap) * DK + scc * 8], &Kl[pp][tid * 8]);    \
        GLDS(&VbT[(size_t)srow * SEQ + (jj)*64 + scc * 8], &Vl[pp][tid * 8]);   \
    } while (0)

    const int qrow = qt * QBLK + wv * 16 + c;
    f16x8 bq0 = *(const f16x8*)&Qb[(size_t)qrow * DK + g * 8];      // pre-scaled by CSC
    f16x8 bq1 = *(const f16x8*)&Qb[(size_t)qrow * DK + 32 + g * 8];

    f32x4 acc[4] = {};
    float l_run = 0.f; // per-lane partial; reduced across g-lanes once at the end

    const unsigned long long* mrow = mp + ((size_t)b * SEQ + qrow) * (SEQ / 64);
    unsigned long long wq_cur = mrow[0];

    STAGE_ATTN(0, 0);
    int p = 0;
    for (int j = 0; j < KT_ALL; ++j) {
        __syncthreads(); // drains vmcnt(0): tile j staged in buf p; buf p^1 reads (iter j-1) done
        if (j + 1 < KT_ALL) STAGE_ATTN(j + 1, p ^ 1); // in flight across the whole compute phase
        unsigned long long wq_nxt = (j + 1 < KT_ALL) ? mrow[j + 1] : 0ull; // prefetch (L2)

        // QK^T: incremental K-frag reads (permuted slots), MFMA under setprio
        f32x4 sc[4];
        __builtin_amdgcn_s_setprio(1);
#pragma unroll
        for (int nk = 0; nk < 4; ++nk) {
            int row = nk * 16 + c;
            f16x8 k0 = *(const f16x8*)&Kl[p][row * 64 + ((g ^ (row & 7)) * 8)];
            f16x8 k1 = *(const f16x8*)&Kl[p][row * 64 + (((4 + g) ^ (row & 7)) * 8)];
            f32x4 z = {};
            z = MFMA16(k0, bq0, z);
            z = MFMA16(k1, bq1, z);
            sc[nk] = z;
        }
        __builtin_amdgcn_s_setprio(0);

        // fixed-m softmax on permuted slots; mask bit = (nk&1)*32 + g*8 + (nk>>1)*4 + r
        unsigned long long wq_g = wq_cur >> (g * 8);
        float ps = 0.f;
#pragma unroll
        for (int nk = 0; nk < 4; ++nk) {
            unsigned int nib = (unsigned int)(wq_g >> ((nk & 1) * 32 + (nk >> 1) * 4)) & 0xFu;
#pragma unroll
            for (int r = 0; r < 4; ++r) {
                float pp = EXP2(sc[nk][r]);
                pp = (nib & (1u << r)) ? pp : 0.f;
                sc[nk][r] = pp;
                ps += pp;
            }
        }
        l_run += ps;

        // in-lane pack: D-layout (permuted) IS the PV B-frag layout
        f16x8 pb0, pb1;
#pragma unroll
        for (int j2 = 0; j2 < 2; ++j2)
#pragma unroll
            for (int r = 0; r < 4; ++r) {
                pb0[j2 * 4 + r] = (f16)sc[j2 * 2][r];
                pb1[j2 * 4 + r] = (f16)sc[j2 * 2 + 1][r];
            }

        // PV: incremental V-frag reads, MFMA under setprio
        __builtin_amdgcn_s_setprio(1);
#pragma unroll
        for (int nd = 0; nd < 4; ++nd) {
            int row = nd * 16 + c;
            f16x8 v0 = *(const f16x8*)&Vl[p][row * 64 + ((g ^ (row & 7)) * 8)];
            f16x8 v1 = *(const f16x8*)&Vl[p][row * 64 + (((4 + g) ^ (row & 7)) * 8)];
            acc[nd] = MFMA16(v0, pb0, acc[nd]);
            acc[nd] = MFMA16(v1, pb1, acc[nd]);
        }
        __builtin_amdgcn_s_setprio(0);

        wq_cur = wq_nxt;
        p ^= 1;
    }

    // deferred l reduction across the 4 g-lanes holding this q-row
    l_run += __shfl_xor(l_run, 16);
    l_run += __shfl_xor(l_run, 32);

    {
        float inv = l_run > 0.f ? 1.0f / l_run : 0.f;
#pragma unroll
        for (int nd = 0; nd < 4; ++nd) {
            f16x4 o;
#pragma unroll
            for (int r = 0; r < 4; ++r) o[r] = (f16)(acc[nd][r] * inv);
            *(f16x4*)&Xo[((size_t)(b * SEQ) + qrow) * DM + hh * DK + nd * 16 + g * 4] = o;
        }
    }
#undef STAGE_ATTN
}

extern "C" void kernel_launch(void* const* d_in, const int* in_sizes, int n_in,
                              void* d_out, int out_size, void* d_ws, size_t ws_size,
                              hipStream_t stream) {
    const float* query = (const float*)d_in[0];
    const float* key_ = (const float*)d_in[1];
    const float* value = (const float*)d_in[2];
    const int* mask = (const int*)d_in[3];
    const float* Wq = (const float*)d_in[4];
    const float* bq = (const float*)d_in[5];
    const float* Wk = (const float*)d_in[6];
    const float* bk = (const float*)d_in[7];
    const float* Wv = (const float*)d_in[8];
    const float* bv = (const float*)d_in[9];
    const float* Wo = (const float*)d_in[10];
    const float* bo = (const float*)d_in[11];
    float* out = (float*)d_out;

    // ws layout (58 MiB): mp(1M) | Qh | Kh | VhT | Xhq(->Xo) | Xhk | Xhv | Wt
    // VhT slot: gemm_qkv2 z=2 writes V transposed there directly.
    // Xhq slot: prep writes X_q f16 -> gemm_qkv reads it -> attn writes Xo there -> gemm_out reads Xo.
    char* ws = (char*)d_ws;
    const size_t headsz = (size_t)NBATCH * NHEAD * SEQ * DK * sizeof(f16); // 8 MiB
    unsigned long long* mp = (unsigned long long*)(ws);
    f16* Qh = (f16*)(ws + (1 << 20));
    f16* Kh = (f16*)(ws + (1 << 20) + headsz);
    f16* VhT = (f16*)(ws + (1 << 20) + 2 * headsz);
    f16* Xhq = (f16*)(ws + (1 << 20) + 3 * headsz);
    f16* Xhk = (f16*)(ws + (1 << 20) + 4 * headsz);
    f16* Xhv = (f16*)(ws + (1 << 20) + 5 * headsz);
    f16* Wt = (f16*)(ws + (1 << 20) + 6 * headsz); // 4 x [1024][1024] f16
    f16* Xo = Xhq;

    hipLaunchKernelGGL(prep_k, dim3(M_TOT * DM / (8 * 256), 1, 5), dim3(256), 0, stream,
                       mask, mp, query, key_, value, Xhq, Xhk, Xhv, Wq, Wk, Wv, Wo, Wt);
    hipLaunchKernelGGL(gemm_qkv2_k, dim3(DM / 128, M_TOT / 128, 3), dim3(256), 0, stream,
                       Xhq, Xhk, Xhv, Wt, bq, bk, bv, Qh, Kh, VhT);
    hipLaunchKernelGGL(attn_k, dim3(SEQ / QBLK * NHEAD * NBATCH), dim3(512), 0, stream,
                       Qh, Kh, VhT, mp, Xo);
    hipLaunchKernelGGL(gemm_out2_k, dim3(DM / 128, M_TOT / 128), dim3(256), 0, stream,
                       Xo, Wt + (size_t)3 * DM * DM, bo, out);
}

// Round 22
// 154.597 us; speedup vs baseline: 1.0315x; 1.0065x over previous
//
#include <hip/hip_runtime.h>

typedef _Float16 f16;
typedef __attribute__((ext_vector_type(2))) _Float16 f16x2;
typedef __attribute__((ext_vector_type(4))) _Float16 f16x4;
typedef __attribute__((ext_vector_type(8))) _Float16 f16x8;
typedef __attribute__((ext_vector_type(4))) float f32x4;
typedef __attribute__((ext_vector_type(2))) __fp16 fp16x2; // native type for cvt_pkrtz/fdot2

#define MFMA16(A_, B_, C_) __builtin_amdgcn_mfma_f32_16x16x32_f16(A_, B_, C_, 0, 0, 0)
#define EXP2(x) __builtin_amdgcn_exp2f(x) /* bare v_exp_f32 (R12: OCML exp2f safe-path dominated VALU) */

#define NHEAD 16
#define SEQ 2048
#define DM 1024
#define DK 64
#define NBATCH 2
#define M_TOT (NBATCH * SEQ) /* 4096 */
#define CSC 0.18033688011112042f /* 0.125 * log2(e), folded into Wq/bq */

// direct-to-LDS 16B staging (per-lane global addr, linear LDS dest)
#define GLDS(gp, lp)                                                                     \
    __builtin_amdgcn_global_load_lds((const __attribute__((address_space(1))) void*)(gp), \
                                     (__attribute__((address_space(3))) void*)(lp), 16, 0, 0)

// ---------------- fused prep: mask bit-pack + X fp32->f16 + W transpose (1 launch) ----------------
__global__ __launch_bounds__(256) void prep_k(
    const int* __restrict__ mask, unsigned long long* __restrict__ mp,
    const float* __restrict__ xq, const float* __restrict__ xk, const float* __restrict__ xv,
    f16* __restrict__ oq, f16* __restrict__ ok, f16* __restrict__ ov,
    const float* __restrict__ Wq, const float* __restrict__ Wk,
    const float* __restrict__ Wv, const float* __restrict__ Wo, f16* __restrict__ Wt) {
    __shared__ float T[64][65];
    const int z = blockIdx.z, bx = blockIdx.x, tid = threadIdx.x;
    if (z < 3) {
        const float* src = z == 0 ? xq : (z == 1 ? xk : xv);
        f16* dst = z == 0 ? oq : (z == 1 ? ok : ov);
        size_t i = ((size_t)bx * 256 + tid) * 8;
        float4 a = *(const float4*)&src[i];
        float4 b = *(const float4*)&src[i + 4];
        f16x8 h;
        h[0] = (f16)a.x; h[1] = (f16)a.y; h[2] = (f16)a.z; h[3] = (f16)a.w;
        h[4] = (f16)b.x; h[5] = (f16)b.y; h[6] = (f16)b.z; h[7] = (f16)b.w;
        *(f16x8*)&dst[i] = h;
    } else if (z == 3) {
        if (bx >= 1024) return;
        const int zz = bx >> 8, t = bx & 255;
        const float* W = zz == 0 ? Wq : (zz == 1 ? Wk : (zz == 2 ? Wv : Wo));
        const float wsc = zz == 0 ? CSC : 1.0f;
        f16* out = Wt + (size_t)zz * DM * DM;
        const int k0 = (t >> 4) * 64, n0 = (t & 15) * 64;
        const int r = tid >> 2, q = tid & 3;
        const float4* s = (const float4*)&W[(size_t)(k0 + r) * DM + n0 + q * 16];
        float4 v0 = s[0], v1 = s[1], v2 = s[2], v3 = s[3];
        T[r][q * 16 + 0] = v0.x; T[r][q * 16 + 1] = v0.y; T[r][q * 16 + 2] = v0.z; T[r][q * 16 + 3] = v0.w;
        T[r][q * 16 + 4] = v1.x; T[r][q * 16 + 5] = v1.y; T[r][q * 16 + 6] = v1.z; T[r][q * 16 + 7] = v1.w;
        T[r][q * 16 + 8] = v2.x; T[r][q * 16 + 9] = v2.y; T[r][q * 16 + 10] = v2.z; T[r][q * 16 + 11] = v2.w;
        T[r][q * 16 + 12] = v3.x; T[r][q * 16 + 13] = v3.y; T[r][q * 16 + 14] = v3.z; T[r][q * 16 + 15] = v3.w;
        __syncthreads();
        f16x8 h0, h1;
#pragma unroll
        for (int j = 0; j < 8; ++j) {
            h0[j] = (f16)(T[q * 16 + j][r] * wsc);
            h1[j] = (f16)(T[q * 16 + 8 + j][r] * wsc);
        }
        *(f16x8*)&out[(size_t)(n0 + r) * DM + k0 + q * 16] = h0;
        *(f16x8*)&out[(size_t)(n0 + r) * DM + k0 + q * 16 + 8] = h1;
    } else {
        if (bx >= 512) return;
        int lane = tid & 63;
        int gw = (bx * 256 + tid) >> 6;
        const int nw = (512 * 256) >> 6;
        const int nwords = NBATCH * SEQ * (SEQ / 64);
        for (int w = gw; w < nwords; w += nw) {
            int v = mask[(size_t)w * 64 + lane];
            unsigned long long bits = __ballot(v != 0);
            if (lane == 0) mp[w] = bits;
        }
    }
}

// ---------------- f16 GEMM core: C[128x128] = A[128xK] . Bt[128xK]^T, K=1024 ----------------
__device__ __forceinline__ void gemm_core(const f16* __restrict__ A, const f16* __restrict__ Bt,
                                          int m0, int n0, f16* Al, f16* Bl, f32x4 acc[4][4], int tid) {
    const int lane = tid & 63;
    const int wv = tid >> 6;
    const int wr = wv >> 1, wc = wv & 1;
    const int g = lane >> 4, c = lane & 15;

    for (int k0 = 0; k0 < DM; k0 += 64) {
#pragma unroll
        for (int j = 0; j < 4; ++j) {
            int chunk = j * 256 + tid;  // 0..1023
            int row = chunk >> 3, cc = chunk & 7;
            int ccs = cc ^ (row & 7);
            GLDS(&A[(size_t)(m0 + row) * DM + k0 + ccs * 8], &Al[chunk * 8]);
        }
#pragma unroll
        for (int j = 0; j < 4; ++j) {
            int chunk = j * 256 + tid;
            int row = chunk >> 3, cc = chunk & 7;
            int ccs = cc ^ (row & 7);
            GLDS(&Bt[(size_t)(n0 + row) * DM + k0 + ccs * 8], &Bl[chunk * 8]);
        }
        __syncthreads();  // compiler drains vmcnt(0): tile staged
#pragma unroll
        for (int ks = 0; ks < 2; ++ks) {
            f16x8 af[4], bf[4];
#pragma unroll
            for (int mi = 0; mi < 4; ++mi) {
                int row = wr * 64 + mi * 16 + c;
                af[mi] = *(const f16x8*)&Al[row * 64 + ((ks * 4 + g) ^ (row & 7)) * 8];
            }
#pragma unroll
            for (int ni = 0; ni < 4; ++ni) {
                int row = wc * 64 + ni * 16 + c;
                bf[ni] = *(const f16x8*)&Bl[row * 64 + ((ks * 4 + g) ^ (row & 7)) * 8];
            }
#pragma unroll
            for (int mi = 0; mi < 4; ++mi)
#pragma unroll
                for (int ni = 0; ni < 4; ++ni)
                    acc[mi][ni] = MFMA16(af[mi], bf[ni], acc[mi][ni]);
        }
        __syncthreads();  // frag reads done before next stage overwrites
    }
}

// XCD-aware chunked block swizzle (T1): 256 wg per z-slice, 8 XCDs, 32 wg/XCD chunk.
__device__ __forceinline__ void xcd_swizzle(int& bx, int& by, int gdx) {
    int lin = by * gdx + bx;
    int nl = (lin & 7) * 32 + (lin >> 3); // bijective: 256 = 8*32
    bx = nl % gdx;
    by = nl / gdx;
}

// ---------------- QKV projection: f16 Xh . Wt + b -> Q/K per-head [B,H,S,DK]; V -> VhT [B,H,DK,S] ----------------
__global__ __launch_bounds__(256) void gemm_qkv2_k(
    const f16* __restrict__ Xq, const f16* __restrict__ Xk, const f16* __restrict__ Xv,
    const f16* __restrict__ Wt, const float* __restrict__ bq, const float* __restrict__ bk,
    const float* __restrict__ bv, f16* __restrict__ Qh, f16* __restrict__ Kh, f16* __restrict__ VhT) {
    __shared__ f16 Al[128 * 64];
    __shared__ f16 Bl[128 * 64];
    const int which = blockIdx.z;
    const f16* A = which == 0 ? Xq : (which == 1 ? Xk : Xv);
    const f16* Bt = Wt + (size_t)which * DM * DM;
    const float* bias = which == 0 ? bq : (which == 1 ? bk : bv);

    const int tid = threadIdx.x, lane = tid & 63, wv = tid >> 6;
    const int wr = wv >> 1, wc = wv & 1, g = lane >> 4, c = lane & 15;
    int bx = blockIdx.x, by = blockIdx.y;
    xcd_swizzle(bx, by, gridDim.x);
    const int m0 = by * 128, n0 = bx * 128;

    f32x4 acc[4][4] = {};
    gemm_core(A, Bt, m0, n0, Al, Bl, acc, tid);

    const float bsc = which == 0 ? CSC : 1.0f; // CSC folded into Wq; fold into bq too
    if (which == 2) {
        // V epilogue writes transposed VhT[b,h,d,s]: 4 consecutive m = consecutive s -> f16x4
#pragma unroll
        for (int ni = 0; ni < 4; ++ni) {
            int n = n0 + wc * 64 + ni * 16 + c;
            float bias_n = bias[n];
            int hh = n >> 6, d = n & 63;
#pragma unroll
            for (int mi = 0; mi < 4; ++mi) {
                int mbase = m0 + wr * 64 + mi * 16 + g * 4;
                int bb = mbase >> 11, s = mbase & (SEQ - 1);
                f16x4 o;
#pragma unroll
                for (int r = 0; r < 4; ++r) o[r] = (f16)(acc[mi][ni][r] + bias_n);
                *(f16x4*)&VhT[(((size_t)(bb * NHEAD + hh)) * DK + d) * SEQ + s] = o;
            }
        }
    } else {
        f16* OUT = which == 0 ? Qh : Kh;
#pragma unroll
        for (int ni = 0; ni < 4; ++ni) {
            int n = n0 + wc * 64 + ni * 16 + c;
            float bias_n = bias[n] * bsc;
            int hh = n >> 6, d = n & 63;
#pragma unroll
            for (int mi = 0; mi < 4; ++mi) {
                int mbase = m0 + wr * 64 + mi * 16 + g * 4;
#pragma unroll
                for (int r = 0; r < 4; ++r) {
                    int m = mbase + r;
                    int bb = m >> 11, s = m & (SEQ - 1);
                    OUT[(((size_t)(bb * NHEAD + hh)) * SEQ + s) * DK + d] = (f16)(acc[mi][ni][r] + bias_n);
                }
            }
        }
    }
}

// ---------------- output projection: f16 Xo . Wto + bo -> fp32 [M][DM] ----------------
__global__ __launch_bounds__(256) void gemm_out2_k(
    const f16* __restrict__ Xo, const f16* __restrict__ Wto, const float* __restrict__ bo,
    float* __restrict__ OUT) {
    __shared__ f16 Al[128 * 64];
    __shared__ f16 Bl[128 * 64];
    const int tid = threadIdx.x, lane = tid & 63, wv = tid >> 6;
    const int wr = wv >> 1, wc = wv & 1, g = lane >> 4, c = lane & 15;
    int bx = blockIdx.x, by = blockIdx.y;
    xcd_swizzle(bx, by, gridDim.x);
    const int m0 = by * 128, n0 = bx * 128;

    f32x4 acc[4][4] = {};
    gemm_core(Xo, Wto, m0, n0, Al, Bl, acc, tid);

#pragma unroll
    for (int ni = 0; ni < 4; ++ni) {
        int n = n0 + wc * 64 + ni * 16 + c;
        float bias_n = bo[n];
#pragma unroll
        for (int mi = 0; mi < 4; ++mi) {
            int mbase = m0 + wr * 64 + mi * 16 + g * 4;
#pragma unroll
            for (int r = 0; r < 4; ++r) {
                int m = mbase + r;
                OUT[(size_t)m * DM + n] = acc[mi][ni][r] + bias_n;
            }
        }
    }
}

// ---------------- flash attention: single pass + permuted-K + packed softmax ----------------
// Structure = R21 (best measured). R22 adds packed softmax: cvt_pkrtz packs P pairs
// (8 packed cvt replace 16 scalar), fdot2(P,(1,1)) accumulates l (8 dot2 replace 16
// scalar adds) -> ~16 fewer VALU ops per kt-wave. Summing the f16-rounded P also makes
// l exactly consistent with the P used by PV.
// PERMUTED K: LDS key-slot s (bits s5..s0) holds key kap(s) = s4*32 + (s3s2)*8 + s5*4 + (s1s0);
// QK^T's D-layout output IS PV's B-frag layout; mask bit = (nk&1)*32 + g*8 + (nk>>1)*4 + r.
// Single pass over 32 kt, direct normalized Xo write, XCD head-affinity decode.
// FIXED m=0 softmax (R9), bare v_exp_f32 (R12), l-reduce deferred, Q pre-scaled by CSC.
#define QBLK 128
#define KT_ALL (SEQ / 64) /* 32 */

__global__ __launch_bounds__(512) void attn_k(
    const f16* __restrict__ Qh, const f16* __restrict__ Kh, const f16* __restrict__ VhT,
    const unsigned long long* __restrict__ mp, f16* __restrict__ Xo) {
    __shared__ f16 Kl[2][4096]; // [key-slot][d] tiles, swizzled 16B chunks (16 KB)
    __shared__ f16 Vl[2][4096]; // [d][key] tiles (from VhT), swizzled (16 KB)

    const int tid = threadIdx.x, lane = tid & 63, wv = tid >> 6;
    const int g = lane >> 4, c = lane & 15;
    const int lin = blockIdx.x;          // 512 blocks
    const int key = lin & 31;            // b*16 + hh : lin&7 == hh&7 -> XCD affinity
    const int qt = lin >> 5;             // 0..15
    const int hh = key & (NHEAD - 1), b = key >> 4;
    const size_t headoff = ((size_t)(b * NHEAD + hh)) * SEQ * DK;
    const f16* Qb = Qh + headoff;
    const f16* Kb = Kh + headoff;
    const f16* VbT = VhT + headoff; // [DK][SEQ] rows

    // staging: 512 chunks of 16B per tile, 1 per thread per tile
    const int srow = tid >> 3, scc = (tid & 7) ^ (srow & 7);
    // permuted source key for K-slot srow
    const int kap = ((srow >> 4) & 1) * 32 + ((srow >> 2) & 3) * 8 + ((srow >> 5) & 1) * 4 + (srow & 3);

#define STAGE_ATTN(jj, pp)                                                      \
    do {                                                                        \
        GLDS(&Kb[(size_t)((jj)*64 + kap) * DK + scc * 8], &Kl[pp][tid * 8]);    \
        GLDS(&VbT[(size_t)srow * SEQ + (jj)*64 + scc * 8], &Vl[pp][tid * 8]);   \
    } while (0)

    const int qrow = qt * QBLK + wv * 16 + c;
    f16x8 bq0 = *(const f16x8*)&Qb[(size_t)qrow * DK + g * 8];      // pre-scaled by CSC
    f16x8 bq1 = *(const f16x8*)&Qb[(size_t)qrow * DK + 32 + g * 8];

    f32x4 acc[4] = {};
    float l_run = 0.f; // per-lane partial; reduced across g-lanes once at the end
    const fp16x2 ones = {(__fp16)1.0f, (__fp16)1.0f};

    const unsigned long long* mrow = mp + ((size_t)b * SEQ + qrow) * (SEQ / 64);
    unsigned long long wq_cur = mrow[0];

    STAGE_ATTN(0, 0);
    int p = 0;
    for (int j = 0; j < KT_ALL; ++j) {
        __syncthreads(); // drains vmcnt(0): tile j staged in buf p; buf p^1 reads (iter j-1) done
        if (j + 1 < KT_ALL) STAGE_ATTN(j + 1, p ^ 1); // in flight across the whole compute phase
        unsigned long long wq_nxt = (j + 1 < KT_ALL) ? mrow[j + 1] : 0ull; // prefetch (L2)

        // QK^T: incremental K-frag reads (permuted slots), MFMA under setprio
        f32x4 sc[4];
        __builtin_amdgcn_s_setprio(1);
#pragma unroll
        for (int nk = 0; nk < 4; ++nk) {
            int row = nk * 16 + c;
            f16x8 k0 = *(const f16x8*)&Kl[p][row * 64 + ((g ^ (row & 7)) * 8)];
            f16x8 k1 = *(const f16x8*)&Kl[p][row * 64 + (((4 + g) ^ (row & 7)) * 8)];
            f32x4 z = {};
            z = MFMA16(k0, bq0, z);
            z = MFMA16(k1, bq1, z);
            sc[nk] = z;
        }
        __builtin_amdgcn_s_setprio(0);

        // fixed-m softmax: exp -> mask -> packed f16 pairs (pb frags) -> l via fdot2
        unsigned long long wq_g = wq_cur >> (g * 8);
        union { unsigned int u[4]; f16x8 v; } U0, U1;
#pragma unroll
        for (int nk = 0; nk < 4; ++nk) {
            unsigned int nib = (unsigned int)(wq_g >> ((nk & 1) * 32 + (nk >> 1) * 4)) & 0xFu;
            float p0 = EXP2(sc[nk][0]); p0 = (nib & 1u) ? p0 : 0.f;
            float p1 = EXP2(sc[nk][1]); p1 = (nib & 2u) ? p1 : 0.f;
            float p2 = EXP2(sc[nk][2]); p2 = (nib & 4u) ? p2 : 0.f;
            float p3 = EXP2(sc[nk][3]); p3 = (nib & 8u) ? p3 : 0.f;
            fp16x2 w01 = __builtin_amdgcn_cvt_pkrtz(p0, p1);
            fp16x2 w23 = __builtin_amdgcn_cvt_pkrtz(p2, p3);
            l_run = __builtin_amdgcn_fdot2(w01, ones, l_run, false);
            l_run = __builtin_amdgcn_fdot2(w23, ones, l_run, false);
            // assemble PV B-frags: nk even -> pb0 half (nk>>1), nk odd -> pb1 half
            unsigned int uw01 = *(unsigned int*)&w01;
            unsigned int uw23 = *(unsigned int*)&w23;
            if (nk & 1) {
                U1.u[(nk >> 1) * 2] = uw01;
                U1.u[(nk >> 1) * 2 + 1] = uw23;
            } else {
                U0.u[(nk >> 1) * 2] = uw01;
                U0.u[(nk >> 1) * 2 + 1] = uw23;
            }
        }
        f16x8 pb0 = U0.v;
        f16x8 pb1 = U1.v;

        // PV: incremental V-frag reads, MFMA under setprio
        __builtin_amdgcn_s_setprio(1);
#pragma unroll
        for (int nd = 0; nd < 4; ++nd) {
            int row = nd * 16 + c;
            f16x8 v0 = *(const f16x8*)&Vl[p][row * 64 + ((g ^ (row & 7)) * 8)];
            f16x8 v1 = *(const f16x8*)&Vl[p][row * 64 + (((4 + g) ^ (row & 7)) * 8)];
            acc[nd] = MFMA16(v0, pb0, acc[nd]);
            acc[nd] = MFMA16(v1, pb1, acc[nd]);
        }
        __builtin_amdgcn_s_setprio(0);

        wq_cur = wq_nxt;
        p ^= 1;
    }

    // deferred l reduction across the 4 g-lanes holding this q-row
    l_run += __shfl_xor(l_run, 16);
    l_run += __shfl_xor(l_run, 32);

    {
        float inv = l_run > 0.f ? 1.0f / l_run : 0.f;
#pragma unroll
        for (int nd = 0; nd < 4; ++nd) {
            f16x4 o;
#pragma unroll
            for (int r = 0; r < 4; ++r) o[r] = (f16)(acc[nd][r] * inv);
            *(f16x4*)&Xo[((size_t)(b * SEQ) + qrow) * DM + hh * DK + nd * 16 + g * 4] = o;
        }
    }
#undef STAGE_ATTN
}

extern "C" void kernel_launch(void* const* d_in, const int* in_sizes, int n_in,
                              void* d_out, int out_size, void* d_ws, size_t ws_size,
                              hipStream_t stream) {
    const float* query = (const float*)d_in[0];
    const float* key_ = (const float*)d_in[1];
    const float* value = (const float*)d_in[2];
    const int* mask = (const int*)d_in[3];
    const float* Wq = (const float*)d_in[4];
    const float* bq = (const float*)d_in[5];
    const float* Wk = (const float*)d_in[6];
    const float* bk = (const float*)d_in[7];
    const float* Wv = (const float*)d_in[8];
    const float* bv = (const float*)d_in[9];
    const float* Wo = (const float*)d_in[10];
    const float* bo = (const float*)d_in[11];
    float* out = (float*)d_out;

    // ws layout (58 MiB): mp(1M) | Qh | Kh | VhT | Xhq(->Xo) | Xhk | Xhv | Wt
    char* ws = (char*)d_ws;
    const size_t headsz = (size_t)NBATCH * NHEAD * SEQ * DK * sizeof(f16); // 8 MiB
    unsigned long long* mp = (unsigned long long*)(ws);
    f16* Qh = (f16*)(ws + (1 << 20));
    f16* Kh = (f16*)(ws + (1 << 20) + headsz);
    f16* VhT = (f16*)(ws + (1 << 20) + 2 * headsz);
    f16* Xhq = (f16*)(ws + (1 << 20) + 3 * headsz);
    f16* Xhk = (f16*)(ws + (1 << 20) + 4 * headsz);
    f16* Xhv = (f16*)(ws + (1 << 20) + 5 * headsz);
    f16* Wt = (f16*)(ws + (1 << 20) + 6 * headsz); // 4 x [1024][1024] f16
    f16* Xo = Xhq;

    hipLaunchKernelGGL(prep_k, dim3(M_TOT * DM / (8 * 256), 1, 5), dim3(256), 0, stream,
                       mask, mp, query, key_, value, Xhq, Xhk, Xhv, Wq, Wk, Wv, Wo, Wt);
    hipLaunchKernelGGL(gemm_qkv2_k, dim3(DM / 128, M_TOT / 128, 3), dim3(256), 0, stream,
                       Xhq, Xhk, Xhv, Wt, bq, bk, bv, Qh, Kh, VhT);
    hipLaunchKernelGGL(attn_k, dim3(SEQ / QBLK * NHEAD * NBATCH), dim3(512), 0, stream,
                       Qh, Kh, VhT, mp, Xo);
    hipLaunchKernelGGL(gemm_out2_k, dim3(DM / 128, M_TOT / 128), dim3(256), 0, stream,
                       Xo, Wt + (size_t)3 * DM * DM, bo, out);
}

// Round 23
// 152.060 us; speedup vs baseline: 1.0487x; 1.0167x over previous
//
#include <hip/hip_runtime.h>

typedef _Float16 f16;
typedef __attribute__((ext_vector_type(2))) _Float16 f16x2;
typedef __attribute__((ext_vector_type(4))) _Float16 f16x4;
typedef __attribute__((ext_vector_type(8))) _Float16 f16x8;
typedef __attribute__((ext_vector_type(4))) float f32x4;
typedef __attribute__((ext_vector_type(2))) __fp16 fp16x2; // native type for cvt_pkrtz/fdot2

#define MFMA16(A_, B_, C_) __builtin_amdgcn_mfma_f32_16x16x32_f16(A_, B_, C_, 0, 0, 0)
#define EXP2(x) __builtin_amdgcn_exp2f(x) /* bare v_exp_f32 (R12: OCML exp2f safe-path dominated VALU) */

#define NHEAD 16
#define SEQ 2048
#define DM 1024
#define DK 64
#define NBATCH 2
#define M_TOT (NBATCH * SEQ) /* 4096 */
#define CSC 0.18033688011112042f /* 0.125 * log2(e), folded into Wq/bq */

// direct-to-LDS 16B staging (per-lane global addr, linear LDS dest)
#define GLDS(gp, lp)                                                                     \
    __builtin_amdgcn_global_load_lds((const __attribute__((address_space(1))) void*)(gp), \
                                     (__attribute__((address_space(3))) void*)(lp), 16, 0, 0)

// ---------------- fused prep: mask bit-pack + X fp32->f16 + W transpose (1 launch) ----------------
__global__ __launch_bounds__(256) void prep_k(
    const int* __restrict__ mask, unsigned long long* __restrict__ mp,
    const float* __restrict__ xq, const float* __restrict__ xk, const float* __restrict__ xv,
    f16* __restrict__ oq, f16* __restrict__ ok, f16* __restrict__ ov,
    const float* __restrict__ Wq, const float* __restrict__ Wk,
    const float* __restrict__ Wv, const float* __restrict__ Wo, f16* __restrict__ Wt) {
    __shared__ float T[64][65];
    const int z = blockIdx.z, bx = blockIdx.x, tid = threadIdx.x;
    if (z < 3) {
        const float* src = z == 0 ? xq : (z == 1 ? xk : xv);
        f16* dst = z == 0 ? oq : (z == 1 ? ok : ov);
        size_t i = ((size_t)bx * 256 + tid) * 8;
        float4 a = *(const float4*)&src[i];
        float4 b = *(const float4*)&src[i + 4];
        f16x8 h;
        h[0] = (f16)a.x; h[1] = (f16)a.y; h[2] = (f16)a.z; h[3] = (f16)a.w;
        h[4] = (f16)b.x; h[5] = (f16)b.y; h[6] = (f16)b.z; h[7] = (f16)b.w;
        *(f16x8*)&dst[i] = h;
    } else if (z == 3) {
        if (bx >= 1024) return;
        const int zz = bx >> 8, t = bx & 255;
        const float* W = zz == 0 ? Wq : (zz == 1 ? Wk : (zz == 2 ? Wv : Wo));
        const float wsc = zz == 0 ? CSC : 1.0f;
        f16* out = Wt + (size_t)zz * DM * DM;
        const int k0 = (t >> 4) * 64, n0 = (t & 15) * 64;
        const int r = tid >> 2, q = tid & 3;
        const float4* s = (const float4*)&W[(size_t)(k0 + r) * DM + n0 + q * 16];
        float4 v0 = s[0], v1 = s[1], v2 = s[2], v3 = s[3];
        T[r][q * 16 + 0] = v0.x; T[r][q * 16 + 1] = v0.y; T[r][q * 16 + 2] = v0.z; T[r][q * 16 + 3] = v0.w;
        T[r][q * 16 + 4] = v1.x; T[r][q * 16 + 5] = v1.y; T[r][q * 16 + 6] = v1.z; T[r][q * 16 + 7] = v1.w;
        T[r][q * 16 + 8] = v2.x; T[r][q * 16 + 9] = v2.y; T[r][q * 16 + 10] = v2.z; T[r][q * 16 + 11] = v2.w;
        T[r][q * 16 + 12] = v3.x; T[r][q * 16 + 13] = v3.y; T[r][q * 16 + 14] = v3.z; T[r][q * 16 + 15] = v3.w;
        __syncthreads();
        f16x8 h0, h1;
#pragma unroll
        for (int j = 0; j < 8; ++j) {
            h0[j] = (f16)(T[q * 16 + j][r] * wsc);
            h1[j] = (f16)(T[q * 16 + 8 + j][r] * wsc);
        }
        *(f16x8*)&out[(size_t)(n0 + r) * DM + k0 + q * 16] = h0;
        *(f16x8*)&out[(size_t)(n0 + r) * DM + k0 + q * 16 + 8] = h1;
    } else {
        if (bx >= 512) return;
        int lane = tid & 63;
        int gw = (bx * 256 + tid) >> 6;
        const int nw = (512 * 256) >> 6;
        const int nwords = NBATCH * SEQ * (SEQ / 64);
        for (int w = gw; w < nwords; w += nw) {
            int v = mask[(size_t)w * 64 + lane];
            unsigned long long bits = __ballot(v != 0);
            if (lane == 0) mp[w] = bits;
        }
    }
}

// ---------------- f16 GEMM core: C[128x128] = A[128xK] . Bt[128xK]^T, K=1024 ----------------
__device__ __forceinline__ void gemm_core(const f16* __restrict__ A, const f16* __restrict__ Bt,
                                          int m0, int n0, f16* Al, f16* Bl, f32x4 acc[4][4], int tid) {
    const int lane = tid & 63;
    const int wv = tid >> 6;
    const int wr = wv >> 1, wc = wv & 1;
    const int g = lane >> 4, c = lane & 15;

    for (int k0 = 0; k0 < DM; k0 += 64) {
#pragma unroll
        for (int j = 0; j < 4; ++j) {
            int chunk = j * 256 + tid;  // 0..1023
            int row = chunk >> 3, cc = chunk & 7;
            int ccs = cc ^ (row & 7);
            GLDS(&A[(size_t)(m0 + row) * DM + k0 + ccs * 8], &Al[chunk * 8]);
        }
#pragma unroll
        for (int j = 0; j < 4; ++j) {
            int chunk = j * 256 + tid;
            int row = chunk >> 3, cc = chunk & 7;
            int ccs = cc ^ (row & 7);
            GLDS(&Bt[(size_t)(n0 + row) * DM + k0 + ccs * 8], &Bl[chunk * 8]);
        }
        __syncthreads();  // compiler drains vmcnt(0): tile staged
#pragma unroll
        for (int ks = 0; ks < 2; ++ks) {
            f16x8 af[4], bf[4];
#pragma unroll
            for (int mi = 0; mi < 4; ++mi) {
                int row = wr * 64 + mi * 16 + c;
                af[mi] = *(const f16x8*)&Al[row * 64 + ((ks * 4 + g) ^ (row & 7)) * 8];
            }
#pragma unroll
            for (int ni = 0; ni < 4; ++ni) {
                int row = wc * 64 + ni * 16 + c;
                bf[ni] = *(const f16x8*)&Bl[row * 64 + ((ks * 4 + g) ^ (row & 7)) * 8];
            }
#pragma unroll
            for (int mi = 0; mi < 4; ++mi)
#pragma unroll
                for (int ni = 0; ni < 4; ++ni)
                    acc[mi][ni] = MFMA16(af[mi], bf[ni], acc[mi][ni]);
        }
        __syncthreads();  // frag reads done before next stage overwrites
    }
}

// XCD-aware chunked block swizzle (T1): 256 wg per z-slice, 8 XCDs, 32 wg/XCD chunk.
__device__ __forceinline__ void xcd_swizzle(int& bx, int& by, int gdx) {
    int lin = by * gdx + bx;
    int nl = (lin & 7) * 32 + (lin >> 3); // bijective: 256 = 8*32
    bx = nl % gdx;
    by = nl / gdx;
}

// ---------------- QKV projection: f16 Xh . Wt + b -> Q/K per-head [B,H,S,DK]; V -> VhT [B,H,DK,S] ----------------
__global__ __launch_bounds__(256) void gemm_qkv2_k(
    const f16* __restrict__ Xq, const f16* __restrict__ Xk, const f16* __restrict__ Xv,
    const f16* __restrict__ Wt, const float* __restrict__ bq, const float* __restrict__ bk,
    const float* __restrict__ bv, f16* __restrict__ Qh, f16* __restrict__ Kh, f16* __restrict__ VhT) {
    __shared__ f16 Al[128 * 64];
    __shared__ f16 Bl[128 * 64];
    const int which = blockIdx.z;
    const f16* A = which == 0 ? Xq : (which == 1 ? Xk : Xv);
    const f16* Bt = Wt + (size_t)which * DM * DM;
    const float* bias = which == 0 ? bq : (which == 1 ? bk : bv);

    const int tid = threadIdx.x, lane = tid & 63, wv = tid >> 6;
    const int wr = wv >> 1, wc = wv & 1, g = lane >> 4, c = lane & 15;
    int bx = blockIdx.x, by = blockIdx.y;
    xcd_swizzle(bx, by, gridDim.x);
    const int m0 = by * 128, n0 = bx * 128;

    f32x4 acc[4][4] = {};
    gemm_core(A, Bt, m0, n0, Al, Bl, acc, tid);

    const float bsc = which == 0 ? CSC : 1.0f; // CSC folded into Wq; fold into bq too
    if (which == 2) {
        // V epilogue writes transposed VhT[b,h,d,s]: 4 consecutive m = consecutive s -> f16x4
#pragma unroll
        for (int ni = 0; ni < 4; ++ni) {
            int n = n0 + wc * 64 + ni * 16 + c;
            float bias_n = bias[n];
            int hh = n >> 6, d = n & 63;
#pragma unroll
            for (int mi = 0; mi < 4; ++mi) {
                int mbase = m0 + wr * 64 + mi * 16 + g * 4;
                int bb = mbase >> 11, s = mbase & (SEQ - 1);
                f16x4 o;
#pragma unroll
                for (int r = 0; r < 4; ++r) o[r] = (f16)(acc[mi][ni][r] + bias_n);
                *(f16x4*)&VhT[(((size_t)(bb * NHEAD + hh)) * DK + d) * SEQ + s] = o;
            }
        }
    } else {
        f16* OUT = which == 0 ? Qh : Kh;
#pragma unroll
        for (int ni = 0; ni < 4; ++ni) {
            int n = n0 + wc * 64 + ni * 16 + c;
            float bias_n = bias[n] * bsc;
            int hh = n >> 6, d = n & 63;
#pragma unroll
            for (int mi = 0; mi < 4; ++mi) {
                int mbase = m0 + wr * 64 + mi * 16 + g * 4;
#pragma unroll
                for (int r = 0; r < 4; ++r) {
                    int m = mbase + r;
                    int bb = m >> 11, s = m & (SEQ - 1);
                    OUT[(((size_t)(bb * NHEAD + hh)) * SEQ + s) * DK + d] = (f16)(acc[mi][ni][r] + bias_n);
                }
            }
        }
    }
}

// ---------------- output projection: f16 Xo . Wto + bo -> fp32 [M][DM] ----------------
__global__ __launch_bounds__(256) void gemm_out2_k(
    const f16* __restrict__ Xo, const f16* __restrict__ Wto, const float* __restrict__ bo,
    float* __restrict__ OUT) {
    __shared__ f16 Al[128 * 64];
    __shared__ f16 Bl[128 * 64];
    const int tid = threadIdx.x, lane = tid & 63, wv = tid >> 6;
    const int wr = wv >> 1, wc = wv & 1, g = lane >> 4, c = lane & 15;
    int bx = blockIdx.x, by = blockIdx.y;
    xcd_swizzle(bx, by, gridDim.x);
    const int m0 = by * 128, n0 = bx * 128;

    f32x4 acc[4][4] = {};
    gemm_core(Xo, Wto, m0, n0, Al, Bl, acc, tid);

#pragma unroll
    for (int ni = 0; ni < 4; ++ni) {
        int n = n0 + wc * 64 + ni * 16 + c;
        float bias_n = bo[n];
#pragma unroll
        for (int mi = 0; mi < 4; ++mi) {
            int mbase = m0 + wr * 64 + mi * 16 + g * 4;
#pragma unroll
            for (int r = 0; r < 4; ++r) {
                int m = mbase + r;
                OUT[(size_t)m * DM + n] = acc[mi][ni][r] + bias_n;
            }
        }
    }
}

// ---------------- flash attention: single pass, permuted-K, packed softmax, KVBLK=128 ----------------
// R23: stage TWO 64-key sub-tiles per buffer, ONE barrier per 128 keys (barriers 32->16)
// and two INDEPENDENT sub-tile dependency chains per phase -> compiler interleaves
// sub-tile 1's ds_reads/MFMAs under sub-tile 0's exp2 chain (attacks the latency-bound
// profile; R20 showed LDS-read *throughput* was not the binder). LDS 64KB = 2 blocks/CU,
// exactly the grid-given occupancy (unchanged).
// PERMUTED K (R19): LDS key-slot s holds key kap(s) = s4*32 + (s3s2)*8 + s5*4 + (s1s0);
// QK^T's D-layout IS PV's B-frag layout; mask bit = (nk&1)*32 + g*8 + (nk>>1)*4 + r.
// Packed softmax (R22): cvt_pkrtz + fdot2. FIXED m=0 (R9), bare v_exp_f32 (R12),
// l-reduce deferred, Q pre-scaled by CSC, XCD head-affinity decode (lin&31 = b*16+hh).
#define QBLK 128
#define KVB 128
#define NIT (SEQ / KVB) /* 16 */

__global__ __launch_bounds__(512) void attn_k(
    const f16* __restrict__ Qh, const f16* __restrict__ Kh, const f16* __restrict__ VhT,
    const unsigned long long* __restrict__ mp, f16* __restrict__ Xo) {
    __shared__ f16 Kl[2][2][4096]; // [buf][sub][key-slot*64+d], swizzled 16B chunks (32 KB)
    __shared__ f16 Vl[2][2][4096]; // [buf][sub][d*64+key], swizzled (32 KB)

    const int tid = threadIdx.x, lane = tid & 63, wv = tid >> 6;
    const int g = lane >> 4, c = lane & 15;
    const int lin = blockIdx.x;          // 512 blocks
    const int key = lin & 31;            // b*16 + hh : lin&7 == hh&7 -> XCD affinity
    const int qt = lin >> 5;             // 0..15
    const int hh = key & (NHEAD - 1), b = key >> 4;
    const size_t headoff = ((size_t)(b * NHEAD + hh)) * SEQ * DK;
    const f16* Qb = Qh + headoff;
    const f16* Kb = Kh + headoff;
    const f16* VbT = VhT + headoff; // [DK][SEQ] rows

    // staging: 512 chunks of 16B per 64-key sub-tile, 1 per thread per sub-tile
    const int srow = tid >> 3, scc = (tid & 7) ^ (srow & 7);
    // permuted source key for K-slot srow
    const int kap = ((srow >> 4) & 1) * 32 + ((srow >> 2) & 3) * 8 + ((srow >> 5) & 1) * 4 + (srow & 3);

#define STAGE_ATTN(jj, pp)                                                                    \
    do {                                                                                      \
        GLDS(&Kb[(size_t)((jj)*KVB + kap) * DK + scc * 8], &Kl[pp][0][tid * 8]);              \
        GLDS(&Kb[(size_t)((jj)*KVB + 64 + kap) * DK + scc * 8], &Kl[pp][1][tid * 8]);         \
        GLDS(&VbT[(size_t)srow * SEQ + (jj)*KVB + scc * 8], &Vl[pp][0][tid * 8]);             \
        GLDS(&VbT[(size_t)srow * SEQ + (jj)*KVB + 64 + scc * 8], &Vl[pp][1][tid * 8]);        \
    } while (0)

    const int qrow = qt * QBLK + wv * 16 + c;
    f16x8 bq0 = *(const f16x8*)&Qb[(size_t)qrow * DK + g * 8];      // pre-scaled by CSC
    f16x8 bq1 = *(const f16x8*)&Qb[(size_t)qrow * DK + 32 + g * 8];

    f32x4 acc[4] = {};
    float l_run = 0.f; // per-lane partial; reduced across g-lanes once at the end
    const fp16x2 ones = {(__fp16)1.0f, (__fp16)1.0f};

    const unsigned long long* mrow = mp + ((size_t)b * SEQ + qrow) * (SEQ / 64);
    unsigned long long wq_c0 = mrow[0], wq_c1 = mrow[1];

    STAGE_ATTN(0, 0);
    int p = 0;
    for (int j = 0; j < NIT; ++j) {
        __syncthreads(); // drains vmcnt(0): tile j staged in buf p; buf p^1 reads (iter j-1) done
        if (j + 1 < NIT) STAGE_ATTN(j + 1, p ^ 1); // in flight across the whole compute phase
        unsigned long long wq_n0 = (j + 1 < NIT) ? mrow[2 * j + 2] : 0ull;
        unsigned long long wq_n1 = (j + 1 < NIT) ? mrow[2 * j + 3] : 0ull;

        // two independent 64-key sub-tiles per barrier: compiler interleaves their chains
#pragma unroll
        for (int u = 0; u < 2; ++u) {
            const f16* Klu = Kl[p][u];
            const f16* Vlu = Vl[p][u];
            unsigned long long wq_cur = u ? wq_c1 : wq_c0;

            // QK^T: incremental K-frag reads (permuted slots), MFMA under setprio
            f32x4 sc[4];
            __builtin_amdgcn_s_setprio(1);
#pragma unroll
            for (int nk = 0; nk < 4; ++nk) {
                int row = nk * 16 + c;
                f16x8 k0 = *(const f16x8*)&Klu[row * 64 + ((g ^ (row & 7)) * 8)];
                f16x8 k1 = *(const f16x8*)&Klu[row * 64 + (((4 + g) ^ (row & 7)) * 8)];
                f32x4 z = {};
                z = MFMA16(k0, bq0, z);
                z = MFMA16(k1, bq1, z);
                sc[nk] = z;
            }
            __builtin_amdgcn_s_setprio(0);

            // fixed-m softmax: exp -> mask -> packed f16 pairs -> l via fdot2
            unsigned long long wq_g = wq_cur >> (g * 8);
            union { unsigned int uu[4]; f16x8 v; } U0, U1;
#pragma unroll
            for (int nk = 0; nk < 4; ++nk) {
                unsigned int nib = (unsigned int)(wq_g >> ((nk & 1) * 32 + (nk >> 1) * 4)) & 0xFu;
                float p0 = EXP2(sc[nk][0]); p0 = (nib & 1u) ? p0 : 0.f;
                float p1 = EXP2(sc[nk][1]); p1 = (nib & 2u) ? p1 : 0.f;
                float p2 = EXP2(sc[nk][2]); p2 = (nib & 4u) ? p2 : 0.f;
                float p3 = EXP2(sc[nk][3]); p3 = (nib & 8u) ? p3 : 0.f;
                fp16x2 w01 = __builtin_amdgcn_cvt_pkrtz(p0, p1);
                fp16x2 w23 = __builtin_amdgcn_cvt_pkrtz(p2, p3);
                l_run = __builtin_amdgcn_fdot2(w01, ones, l_run, false);
                l_run = __builtin_amdgcn_fdot2(w23, ones, l_run, false);
                unsigned int uw01 = *(unsigned int*)&w01;
                unsigned int uw23 = *(unsigned int*)&w23;
                if (nk & 1) {
                    U1.uu[(nk >> 1) * 2] = uw01;
                    U1.uu[(nk >> 1) * 2 + 1] = uw23;
                } else {
                    U0.uu[(nk >> 1) * 2] = uw01;
                    U0.uu[(nk >> 1) * 2 + 1] = uw23;
                }
            }
            f16x8 pb0 = U0.v;
            f16x8 pb1 = U1.v;

            // PV: incremental V-frag reads, MFMA under setprio
            __builtin_amdgcn_s_setprio(1);
#pragma unroll
            for (int nd = 0; nd < 4; ++nd) {
                int row = nd * 16 + c;
                f16x8 v0 = *(const f16x8*)&Vlu[row * 64 + ((g ^ (row & 7)) * 8)];
                f16x8 v1 = *(const f16x8*)&Vlu[row * 64 + (((4 + g) ^ (row & 7)) * 8)];
                acc[nd] = MFMA16(v0, pb0, acc[nd]);
                acc[nd] = MFMA16(v1, pb1, acc[nd]);
            }
            __builtin_amdgcn_s_setprio(0);
        }

        wq_c0 = wq_n0;
        wq_c1 = wq_n1;
        p ^= 1;
    }

    // deferred l reduction across the 4 g-lanes holding this q-row
    l_run += __shfl_xor(l_run, 16);
    l_run += __shfl_xor(l_run, 32);

    {
        float inv = l_run > 0.f ? 1.0f / l_run : 0.f;
#pragma unroll
        for (int nd = 0; nd < 4; ++nd) {
            f16x4 o;
#pragma unroll
            for (int r = 0; r < 4; ++r) o[r] = (f16)(acc[nd][r] * inv);
            *(f16x4*)&Xo[((size_t)(b * SEQ) + qrow) * DM + hh * DK + nd * 16 + g * 4] = o;
        }
    }
#undef STAGE_ATTN
}

extern "C" void kernel_launch(void* const* d_in, const int* in_sizes, int n_in,
                              void* d_out, int out_size, void* d_ws, size_t ws_size,
                              hipStream_t stream) {
    const float* query = (const float*)d_in[0];
    const float* key_ = (const float*)d_in[1];
    const float* value = (const float*)d_in[2];
    const int* mask = (const int*)d_in[3];
    const float* Wq = (const float*)d_in[4];
    const float* bq = (const float*)d_in[5];
    const float* Wk = (const float*)d_in[6];
    const float* bk = (const float*)d_in[7];
    const float* Wv = (const float*)d_in[8];
    const float* bv = (const float*)d_in[9];
    const float* Wo = (const float*)d_in[10];
    const float* bo = (const float*)d_in[11];
    float* out = (float*)d_out;

    // ws layout (58 MiB): mp(1M) | Qh | Kh | VhT | Xhq(->Xo) | Xhk | Xhv | Wt
    char* ws = (char*)d_ws;
    const size_t headsz = (size_t)NBATCH * NHEAD * SEQ * DK * sizeof(f16); // 8 MiB
    unsigned long long* mp = (unsigned long long*)(ws);
    f16* Qh = (f16*)(ws + (1 << 20));
    f16* Kh = (f16*)(ws + (1 << 20) + headsz);
    f16* VhT = (f16*)(ws + (1 << 20) + 2 * headsz);
    f16* Xhq = (f16*)(ws + (1 << 20) + 3 * headsz);
    f16* Xhk = (f16*)(ws + (1 << 20) + 4 * headsz);
    f16* Xhv = (f16*)(ws + (1 << 20) + 5 * headsz);
    f16* Wt = (f16*)(ws + (1 << 20) + 6 * headsz); // 4 x [1024][1024] f16
    f16* Xo = Xhq;

    hipLaunchKernelGGL(prep_k, dim3(M_TOT * DM / (8 * 256), 1, 5), dim3(256), 0, stream,
                       mask, mp, query, key_, value, Xhq, Xhk, Xhv, Wq, Wk, Wv, Wo, Wt);
    hipLaunchKernelGGL(gemm_qkv2_k, dim3(DM / 128, M_TOT / 128, 3), dim3(256), 0, stream,
                       Xhq, Xhk, Xhv, Wt, bq, bk, bv, Qh, Kh, VhT);
    hipLaunchKernelGGL(attn_k, dim3(SEQ / QBLK * NHEAD * NBATCH), dim3(512), 0, stream,
                       Qh, Kh, VhT, mp, Xo);
    hipLaunchKernelGGL(gemm_out2_k, dim3(DM / 128, M_TOT / 128), dim3(256), 0, stream,
                       Xo, Wt + (size_t)3 * DM * DM, bo, out);
}

// Round 24
// 150.553 us; speedup vs baseline: 1.0592x; 1.0100x over previous
//
#include <hip/hip_runtime.h>

typedef _Float16 f16;
typedef __attribute__((ext_vector_type(2))) _Float16 f16x2;
typedef __attribute__((ext_vector_type(4))) _Float16 f16x4;
typedef __attribute__((ext_vector_type(8))) _Float16 f16x8;
typedef __attribute__((ext_vector_type(4))) float f32x4;
typedef __attribute__((ext_vector_type(2))) __fp16 fp16x2; // native type for cvt_pkrtz/fdot2

#define MFMA16(A_, B_, C_) __builtin_amdgcn_mfma_f32_16x16x32_f16(A_, B_, C_, 0, 0, 0)
#define EXP2(x) __builtin_amdgcn_exp2f(x) /* bare v_exp_f32 (R12: OCML exp2f safe-path dominated VALU) */

#define NHEAD 16
#define SEQ 2048
#define DM 1024
#define DK 64
#define NBATCH 2
#define M_TOT (NBATCH * SEQ) /* 4096 */
#define CSC 0.18033688011112042f /* 0.125 * log2(e), folded into Wq/bq */

// direct-to-LDS 16B staging (per-lane global addr, linear LDS dest)
#define GLDS(gp, lp)                                                                     \
    __builtin_amdgcn_global_load_lds((const __attribute__((address_space(1))) void*)(gp), \
                                     (__attribute__((address_space(3))) void*)(lp), 16, 0, 0)

// ---------------- fused prep: W transpose + mask bit-pack (X-conversion DELETED, R24) ----------------
// z=0: W^T for 4 matrices (1024 blocks); z=1: pack mask (first 512 blocks).
__global__ __launch_bounds__(256) void prep_k(
    const int* __restrict__ mask, unsigned long long* __restrict__ mp,
    const float* __restrict__ Wq, const float* __restrict__ Wk,
    const float* __restrict__ Wv, const float* __restrict__ Wo, f16* __restrict__ Wt) {
    __shared__ float T[64][65];
    const int z = blockIdx.z, bx = blockIdx.x, tid = threadIdx.x;
    if (z == 0) {
        const int zz = bx >> 8, t = bx & 255;
        const float* W = zz == 0 ? Wq : (zz == 1 ? Wk : (zz == 2 ? Wv : Wo));
        const float wsc = zz == 0 ? CSC : 1.0f;
        f16* out = Wt + (size_t)zz * DM * DM;
        const int k0 = (t >> 4) * 64, n0 = (t & 15) * 64;
        const int r = tid >> 2, q = tid & 3;
        const float4* s = (const float4*)&W[(size_t)(k0 + r) * DM + n0 + q * 16];
        float4 v0 = s[0], v1 = s[1], v2 = s[2], v3 = s[3];
        T[r][q * 16 + 0] = v0.x; T[r][q * 16 + 1] = v0.y; T[r][q * 16 + 2] = v0.z; T[r][q * 16 + 3] = v0.w;
        T[r][q * 16 + 4] = v1.x; T[r][q * 16 + 5] = v1.y; T[r][q * 16 + 6] = v1.z; T[r][q * 16 + 7] = v1.w;
        T[r][q * 16 + 8] = v2.x; T[r][q * 16 + 9] = v2.y; T[r][q * 16 + 10] = v2.z; T[r][q * 16 + 11] = v2.w;
        T[r][q * 16 + 12] = v3.x; T[r][q * 16 + 13] = v3.y; T[r][q * 16 + 14] = v3.z; T[r][q * 16 + 15] = v3.w;
        __syncthreads();
        f16x8 h0, h1;
#pragma unroll
        for (int j = 0; j < 8; ++j) {
            h0[j] = (f16)(T[q * 16 + j][r] * wsc);
            h1[j] = (f16)(T[q * 16 + 8 + j][r] * wsc);
        }
        *(f16x8*)&out[(size_t)(n0 + r) * DM + k0 + q * 16] = h0;
        *(f16x8*)&out[(size_t)(n0 + r) * DM + k0 + q * 16 + 8] = h1;
    } else {
        if (bx >= 512) return;
        int lane = tid & 63;
        int gw = (bx * 256 + tid) >> 6;
        const int nw = (512 * 256) >> 6;
        const int nwords = NBATCH * SEQ * (SEQ / 64);
        for (int w = gw; w < nwords; w += nw) {
            int v = mask[(size_t)w * 64 + lane];
            unsigned long long bits = __ballot(v != 0);
            if (lane == 0) mp[w] = bits;
        }
    }
}

// ---------------- f16 GEMM core (for gemm_out): C[128x128] = A[128xK] . Bt[128xK]^T ----------------
__device__ __forceinline__ void gemm_core(const f16* __restrict__ A, const f16* __restrict__ Bt,
                                          int m0, int n0, f16* Al, f16* Bl, f32x4 acc[4][4], int tid) {
    const int lane = tid & 63;
    const int wv = tid >> 6;
    const int wr = wv >> 1, wc = wv & 1;
    const int g = lane >> 4, c = lane & 15;

    for (int k0 = 0; k0 < DM; k0 += 64) {
#pragma unroll
        for (int j = 0; j < 4; ++j) {
            int chunk = j * 256 + tid;  // 0..1023
            int row = chunk >> 3, cc = chunk & 7;
            int ccs = cc ^ (row & 7);
            GLDS(&A[(size_t)(m0 + row) * DM + k0 + ccs * 8], &Al[chunk * 8]);
        }
#pragma unroll
        for (int j = 0; j < 4; ++j) {
            int chunk = j * 256 + tid;
            int row = chunk >> 3, cc = chunk & 7;
            int ccs = cc ^ (row & 7);
            GLDS(&Bt[(size_t)(n0 + row) * DM + k0 + ccs * 8], &Bl[chunk * 8]);
        }
        __syncthreads();  // compiler drains vmcnt(0): tile staged
#pragma unroll
        for (int ks = 0; ks < 2; ++ks) {
            f16x8 af[4], bf[4];
#pragma unroll
            for (int mi = 0; mi < 4; ++mi) {
                int row = wr * 64 + mi * 16 + c;
                af[mi] = *(const f16x8*)&Al[row * 64 + ((ks * 4 + g) ^ (row & 7)) * 8];
            }
#pragma unroll
            for (int ni = 0; ni < 4; ++ni) {
                int row = wc * 64 + ni * 16 + c;
                bf[ni] = *(const f16x8*)&Bl[row * 64 + ((ks * 4 + g) ^ (row & 7)) * 8];
            }
#pragma unroll
            for (int mi = 0; mi < 4; ++mi)
#pragma unroll
                for (int ni = 0; ni < 4; ++ni)
                    acc[mi][ni] = MFMA16(af[mi], bf[ni], acc[mi][ni]);
        }
        __syncthreads();  // frag reads done before next stage overwrites
    }
}

// XCD-aware chunked block swizzle (T1): 256 wg per z-slice, 8 XCDs, 32 wg/XCD chunk.
__device__ __forceinline__ void xcd_swizzle(int& bx, int& by, int gdx) {
    int lin = by * gdx + bx;
    int nl = (lin & 7) * 32 + (lin >> 3); // bijective: 256 = 8*32
    bx = nl % gdx;
    by = nl / gdx;
}

// ---------------- QKV projection with FUSED f32 A (R24): X fp32 . Wt f16 + b ----------------
// A staged as raw fp32 via GLDS (2048 x 16B chunks, 8/thread/K-step); LDS Al f32 32KB +
// Bl f16 16KB = 48KB -> still 3 blocks/CU. Frag read = 2x ds_read_b128 + 8 RTN cvts,
// both-sides XOR swizzle cc^(row&15) (16-lane phase -> 2 lanes/bank-group = free).
// Deletes prep's X cvt round-trip: -48MB HBM (96 -> 48MB for the A path).
__global__ __launch_bounds__(256) void gemm_qkv2_k(
    const float* __restrict__ Xq, const float* __restrict__ Xk, const float* __restrict__ Xv,
    const f16* __restrict__ Wt, const float* __restrict__ bq, const float* __restrict__ bk,
    const float* __restrict__ bv, f16* __restrict__ Qh, f16* __restrict__ Kh, f16* __restrict__ VhT) {
    __shared__ float Al[128 * 16 * 4]; // [row][16 chunks of 4 f32], swizzled (32 KB)
    __shared__ f16 Bl[128 * 64];       // (16 KB)
    const int which = blockIdx.z;
    const float* A = which == 0 ? Xq : (which == 1 ? Xk : Xv);
    const f16* Bt = Wt + (size_t)which * DM * DM;
    const float* bias = which == 0 ? bq : (which == 1 ? bk : bv);

    const int tid = threadIdx.x, lane = tid & 63, wv = tid >> 6;
    const int wr = wv >> 1, wc = wv & 1, g = lane >> 4, c = lane & 15;
    int bx = blockIdx.x, by = blockIdx.y;
    xcd_swizzle(bx, by, gridDim.x);
    const int m0 = by * 128, n0 = bx * 128;

    f32x4 acc[4][4] = {};

    for (int k0 = 0; k0 < DM; k0 += 64) {
        // A: 2048 chunks of 16B (4 f32), 8 per thread; linear dest, inverse-swz source
#pragma unroll
        for (int j = 0; j < 8; ++j) {
            int q = j * 256 + tid;  // 0..2047
            int row = q >> 4, cc = q & 15;
            int ccs = cc ^ (row & 15);
            GLDS(&A[(size_t)(m0 + row) * DM + k0 + ccs * 4], &Al[q * 4]);
        }
        // B: 1024 chunks (f16), as before
#pragma unroll
        for (int j = 0; j < 4; ++j) {
            int chunk = j * 256 + tid;
            int row = chunk >> 3, cc = chunk & 7;
            int ccs = cc ^ (row & 7);
            GLDS(&Bt[(size_t)(n0 + row) * DM + k0 + ccs * 8], &Bl[chunk * 8]);
        }
        __syncthreads();  // vmcnt(0) drain: tile staged
#pragma unroll
        for (int ks = 0; ks < 2; ++ks) {
            f16x8 af[4], bf[4];
#pragma unroll
            for (int mi = 0; mi < 4; ++mi) {
                int row = wr * 64 + mi * 16 + c;
                int cb = ks * 8 + g * 2;
                f32x4 a0 = *(const f32x4*)&Al[(row * 16 + (cb ^ (row & 15))) * 4];
                f32x4 a1 = *(const f32x4*)&Al[(row * 16 + ((cb + 1) ^ (row & 15))) * 4];
                f16x8 h;
#pragma unroll
                for (int t2 = 0; t2 < 4; ++t2) {
                    h[t2] = (f16)a0[t2];
                    h[4 + t2] = (f16)a1[t2];
                }
                af[mi] = h;
            }
#pragma unroll
            for (int ni = 0; ni < 4; ++ni) {
                int row = wc * 64 + ni * 16 + c;
                bf[ni] = *(const f16x8*)&Bl[row * 64 + ((ks * 4 + g) ^ (row & 7)) * 8];
            }
#pragma unroll
            for (int mi = 0; mi < 4; ++mi)
#pragma unroll
                for (int ni = 0; ni < 4; ++ni)
                    acc[mi][ni] = MFMA16(af[mi], bf[ni], acc[mi][ni]);
        }
        __syncthreads();  // frag reads done before next stage overwrites
    }

    const float bsc = which == 0 ? CSC : 1.0f; // CSC folded into Wq; fold into bq too
    if (which == 2) {
        // V epilogue writes transposed VhT[b,h,d,s]: 4 consecutive m = consecutive s -> f16x4
#pragma unroll
        for (int ni = 0; ni < 4; ++ni) {
            int n = n0 + wc * 64 + ni * 16 + c;
            float bias_n = bias[n];
            int hh = n >> 6, d = n & 63;
#pragma unroll
            for (int mi = 0; mi < 4; ++mi) {
                int mbase = m0 + wr * 64 + mi * 16 + g * 4;
                int bb = mbase >> 11, s = mbase & (SEQ - 1);
                f16x4 o;
#pragma unroll
                for (int r = 0; r < 4; ++r) o[r] = (f16)(acc[mi][ni][r] + bias_n);
                *(f16x4*)&VhT[(((size_t)(bb * NHEAD + hh)) * DK + d) * SEQ + s] = o;
            }
        }
    } else {
        f16* OUT = which == 0 ? Qh : Kh;
#pragma unroll
        for (int ni = 0; ni < 4; ++ni) {
            int n = n0 + wc * 64 + ni * 16 + c;
            float bias_n = bias[n] * bsc;
            int hh = n >> 6, d = n & 63;
#pragma unroll
            for (int mi = 0; mi < 4; ++mi) {
                int mbase = m0 + wr * 64 + mi * 16 + g * 4;
#pragma unroll
                for (int r = 0; r < 4; ++r) {
                    int m = mbase + r;
                    int bb = m >> 11, s = m & (SEQ - 1);
                    OUT[(((size_t)(bb * NHEAD + hh)) * SEQ + s) * DK + d] = (f16)(acc[mi][ni][r] + bias_n);
                }
            }
        }
    }
}

// ---------------- output projection: f16 Xo . Wto + bo -> fp32 [M][DM] ----------------
__global__ __launch_bounds__(256) void gemm_out2_k(
    const f16* __restrict__ Xo, const f16* __restrict__ Wto, const float* __restrict__ bo,
    float* __restrict__ OUT) {
    __shared__ f16 Al[128 * 64];
    __shared__ f16 Bl[128 * 64];
    const int tid = threadIdx.x, lane = tid & 63, wv = tid >> 6;
    const int wr = wv >> 1, wc = wv & 1, g = lane >> 4, c = lane & 15;
    int bx = blockIdx.x, by = blockIdx.y;
    xcd_swizzle(bx, by, gridDim.x);
    const int m0 = by * 128, n0 = bx * 128;

    f32x4 acc[4][4] = {};
    gemm_core(Xo, Wto, m0, n0, Al, Bl, acc, tid);

#pragma unroll
    for (int ni = 0; ni < 4; ++ni) {
        int n = n0 + wc * 64 + ni * 16 + c;
        float bias_n = bo[n];
#pragma unroll
        for (int mi = 0; mi < 4; ++mi) {
            int mbase = m0 + wr * 64 + mi * 16 + g * 4;
#pragma unroll
            for (int r = 0; r < 4; ++r) {
                int m = mbase + r;
                OUT[(size_t)m * DM + n] = acc[mi][ni][r] + bias_n;
            }
        }
    }
}

// ---------------- flash attention: single pass, permuted-K, packed softmax, KVBLK=128 (R23) ----------------
#define QBLK 128
#define KVB 128
#define NIT (SEQ / KVB) /* 16 */

__global__ __launch_bounds__(512) void attn_k(
    const f16* __restrict__ Qh, const f16* __restrict__ Kh, const f16* __restrict__ VhT,
    const unsigned long long* __restrict__ mp, f16* __restrict__ Xo) {
    __shared__ f16 Kl[2][2][4096]; // [buf][sub][key-slot*64+d], swizzled 16B chunks (32 KB)
    __shared__ f16 Vl[2][2][4096]; // [buf][sub][d*64+key], swizzled (32 KB)

    const int tid = threadIdx.x, lane = tid & 63, wv = tid >> 6;
    const int g = lane >> 4, c = lane & 15;
    const int lin = blockIdx.x;          // 512 blocks
    const int key = lin & 31;            // b*16 + hh : lin&7 == hh&7 -> XCD affinity
    const int qt = lin >> 5;             // 0..15
    const int hh = key & (NHEAD - 1), b = key >> 4;
    const size_t headoff = ((size_t)(b * NHEAD + hh)) * SEQ * DK;
    const f16* Qb = Qh + headoff;
    const f16* Kb = Kh + headoff;
    const f16* VbT = VhT + headoff; // [DK][SEQ] rows

    // staging: 512 chunks of 16B per 64-key sub-tile, 1 per thread per sub-tile
    const int srow = tid >> 3, scc = (tid & 7) ^ (srow & 7);
    // permuted source key for K-slot srow
    const int kap = ((srow >> 4) & 1) * 32 + ((srow >> 2) & 3) * 8 + ((srow >> 5) & 1) * 4 + (srow & 3);

#define STAGE_ATTN(jj, pp)                                                                    \
    do {                                                                                      \
        GLDS(&Kb[(size_t)((jj)*KVB + kap) * DK + scc * 8], &Kl[pp][0][tid * 8]);              \
        GLDS(&Kb[(size_t)((jj)*KVB + 64 + kap) * DK + scc * 8], &Kl[pp][1][tid * 8]);         \
        GLDS(&VbT[(size_t)srow * SEQ + (jj)*KVB + scc * 8], &Vl[pp][0][tid * 8]);             \
        GLDS(&VbT[(size_t)srow * SEQ + (jj)*KVB + 64 + scc * 8], &Vl[pp][1][tid * 8]);        \
    } while (0)

    const int qrow = qt * QBLK + wv * 16 + c;
    f16x8 bq0 = *(const f16x8*)&Qb[(size_t)qrow * DK + g * 8];      // pre-scaled by CSC
    f16x8 bq1 = *(const f16x8*)&Qb[(size_t)qrow * DK + 32 + g * 8];

    f32x4 acc[4] = {};
    float l_run = 0.f; // per-lane partial; reduced across g-lanes once at the end
    const fp16x2 ones = {(__fp16)1.0f, (__fp16)1.0f};

    const unsigned long long* mrow = mp + ((size_t)b * SEQ + qrow) * (SEQ / 64);
    unsigned long long wq_c0 = mrow[0], wq_c1 = mrow[1];

    STAGE_ATTN(0, 0);
    int p = 0;
    for (int j = 0; j < NIT; ++j) {
        __syncthreads(); // drains vmcnt(0): tile j staged in buf p; buf p^1 reads (iter j-1) done
        if (j + 1 < NIT) STAGE_ATTN(j + 1, p ^ 1); // in flight across the whole compute phase
        unsigned long long wq_n0 = (j + 1 < NIT) ? mrow[2 * j + 2] : 0ull;
        unsigned long long wq_n1 = (j + 1 < NIT) ? mrow[2 * j + 3] : 0ull;

        // two independent 64-key sub-tiles per barrier: compiler interleaves their chains
#pragma unroll
        for (int u = 0; u < 2; ++u) {
            const f16* Klu = Kl[p][u];
            const f16* Vlu = Vl[p][u];
            unsigned long long wq_cur = u ? wq_c1 : wq_c0;

            // QK^T: incremental K-frag reads (permuted slots), MFMA under setprio
            f32x4 sc[4];
            __builtin_amdgcn_s_setprio(1);
#pragma unroll
            for (int nk = 0; nk < 4; ++nk) {
                int row = nk * 16 + c;
                f16x8 k0 = *(const f16x8*)&Klu[row * 64 + ((g ^ (row & 7)) * 8)];
                f16x8 k1 = *(const f16x8*)&Klu[row * 64 + (((4 + g) ^ (row & 7)) * 8)];
                f32x4 z = {};
                z = MFMA16(k0, bq0, z);
                z = MFMA16(k1, bq1, z);
                sc[nk] = z;
            }
            __builtin_amdgcn_s_setprio(0);

            // fixed-m softmax: exp -> mask -> packed f16 pairs -> l via fdot2
            unsigned long long wq_g = wq_cur >> (g * 8);
            union { unsigned int uu[4]; f16x8 v; } U0, U1;
#pragma unroll
            for (int nk = 0; nk < 4; ++nk) {
                unsigned int nib = (unsigned int)(wq_g >> ((nk & 1) * 32 + (nk >> 1) * 4)) & 0xFu;
                float p0 = EXP2(sc[nk][0]); p0 = (nib & 1u) ? p0 : 0.f;
                float p1 = EXP2(sc[nk][1]); p1 = (nib & 2u) ? p1 : 0.f;
                float p2 = EXP2(sc[nk][2]); p2 = (nib & 4u) ? p2 : 0.f;
                float p3 = EXP2(sc[nk][3]); p3 = (nib & 8u) ? p3 : 0.f;
                fp16x2 w01 = __builtin_amdgcn_cvt_pkrtz(p0, p1);
                fp16x2 w23 = __builtin_amdgcn_cvt_pkrtz(p2, p3);
                l_run = __builtin_amdgcn_fdot2(w01, ones, l_run, false);
                l_run = __builtin_amdgcn_fdot2(w23, ones, l_run, false);
                unsigned int uw01 = *(unsigned int*)&w01;
                unsigned int uw23 = *(unsigned int*)&w23;
                if (nk & 1) {
                    U1.uu[(nk >> 1) * 2] = uw01;
                    U1.uu[(nk >> 1) * 2 + 1] = uw23;
                } else {
                    U0.uu[(nk >> 1) * 2] = uw01;
                    U0.uu[(nk >> 1) * 2 + 1] = uw23;
                }
            }
            f16x8 pb0 = U0.v;
            f16x8 pb1 = U1.v;

            // PV: incremental V-frag reads, MFMA under setprio
            __builtin_amdgcn_s_setprio(1);
#pragma unroll
            for (int nd = 0; nd < 4; ++nd) {
                int row = nd * 16 + c;
                f16x8 v0 = *(const f16x8*)&Vlu[row * 64 + ((g ^ (row & 7)) * 8)];
                f16x8 v1 = *(const f16x8*)&Vlu[row * 64 + (((4 + g) ^ (row & 7)) * 8)];
                acc[nd] = MFMA16(v0, pb0, acc[nd]);
                acc[nd] = MFMA16(v1, pb1, acc[nd]);
            }
            __builtin_amdgcn_s_setprio(0);
        }

        wq_c0 = wq_n0;
        wq_c1 = wq_n1;
        p ^= 1;
    }

    // deferred l reduction across the 4 g-lanes holding this q-row
    l_run += __shfl_xor(l_run, 16);
    l_run += __shfl_xor(l_run, 32);

    {
        float inv = l_run > 0.f ? 1.0f / l_run : 0.f;
#pragma unroll
        for (int nd = 0; nd < 4; ++nd) {
            f16x4 o;
#pragma unroll
            for (int r = 0; r < 4; ++r) o[r] = (f16)(acc[nd][r] * inv);
            *(f16x4*)&Xo[((size_t)(b * SEQ) + qrow) * DM + hh * DK + nd * 16 + g * 4] = o;
        }
    }
#undef STAGE_ATTN
}

extern "C" void kernel_launch(void* const* d_in, const int* in_sizes, int n_in,
                              void* d_out, int out_size, void* d_ws, size_t ws_size,
                              hipStream_t stream) {
    const float* query = (const float*)d_in[0];
    const float* key_ = (const float*)d_in[1];
    const float* value = (const float*)d_in[2];
    const int* mask = (const int*)d_in[3];
    const float* Wq = (const float*)d_in[4];
    const float* bq = (const float*)d_in[5];
    const float* Wk = (const float*)d_in[6];
    const float* bk = (const float*)d_in[7];
    const float* Wv = (const float*)d_in[8];
    const float* bv = (const float*)d_in[9];
    const float* Wo = (const float*)d_in[10];
    const float* bo = (const float*)d_in[11];
    float* out = (float*)d_out;

    // ws layout (58 MiB): mp(1M) | Qh | Kh | VhT | Xo | (2 spare) | Wt
    char* ws = (char*)d_ws;
    const size_t headsz = (size_t)NBATCH * NHEAD * SEQ * DK * sizeof(f16); // 8 MiB
    unsigned long long* mp = (unsigned long long*)(ws);
    f16* Qh = (f16*)(ws + (1 << 20));
    f16* Kh = (f16*)(ws + (1 << 20) + headsz);
    f16* VhT = (f16*)(ws + (1 << 20) + 2 * headsz);
    f16* Xo = (f16*)(ws + (1 << 20) + 3 * headsz);
    f16* Wt = (f16*)(ws + (1 << 20) + 6 * headsz); // 4 x [1024][1024] f16
    
    hipLaunchKernelGGL(prep_k, dim3(1024, 1, 2), dim3(256), 0, stream,
                       mask, mp, Wq, Wk, Wv, Wo, Wt);
    hipLaunchKernelGGL(gemm_qkv2_k, dim3(DM / 128, M_TOT / 128, 3), dim3(256), 0, stream,
                       query, key_, value, Wt, bq, bk, bv, Qh, Kh, VhT);
    hipLaunchKernelGGL(attn_k, dim3(SEQ / QBLK * NHEAD * NBATCH), dim3(512), 0, stream,
                       Qh, Kh, VhT, mp, Xo);
    hipLaunchKernelGGL(gemm_out2_k, dim3(DM / 128, M_TOT / 128), dim3(256), 0, stream,
                       Xo, Wt + (size_t)3 * DM * DM, bo, out);
}